// Round 18
// baseline (247.974 us; speedup 1.0000x reference)
//
#include <hip/hip_runtime.h>
#include <stdint.h>

#define DD   512
#define EE   8

typedef __bf16 bf16x8 __attribute__((ext_vector_type(8)));
typedef float  f32x4  __attribute__((ext_vector_type(4)));
typedef unsigned short u16x8 __attribute__((ext_vector_type(8)));

__device__ __forceinline__ unsigned short f2bf(float f) {  // RTNE
    union { float f; unsigned int i; } v; v.f = f;
    unsigned int x = v.i;
    x += 0x7fffu + ((x >> 16) & 1u);
    return (unsigned short)(x >> 16);
}
__device__ __forceinline__ void gload_lds16(const void* g, void* l) {
    __builtin_amdgcn_global_load_lds(
        (const __attribute__((address_space(1))) unsigned int*)g,
        (__attribute__((address_space(3))) unsigned int*)l, 16, 0, 0);
}
__device__ __forceinline__ f32x4 mfma_bf16(bf16x8 a, bf16x8 b, f32x4 c) {
    return __builtin_amdgcn_mfma_f32_16x16x32_bf16(a, b, c, 0, 0, 0);
}

// ---------- K0: merged prep — W_root^T, W_leaf^T, W_ldec pad^T, W_dec pad^T ----------
__global__ __launch_bounds__(256) void k_prep(
    const float* __restrict__ W_root, const float* __restrict__ W_leaf,
    const float* __restrict__ W_ldec, const float* __restrict__ W_dec,
    unsigned short* __restrict__ WrTh, unsigned short* __restrict__ WlT,
    unsigned short* __restrict__ WldT, unsigned short* __restrict__ WdT)
{
    __shared__ unsigned short tile[64][65];
    int bid = blockIdx.x;            // 864 = 64 (wtr) + 512 (trW) + 256 (trpad) + 32 (trdec)
    int t = threadIdx.x;
    if (bid < 576) {
        const float* src;
        unsigned short* dst;
        int tl;
        if (bid < 64) {
            src = W_root; dst = WrTh; tl = bid;
        } else {
            int e = (bid - 64) >> 6;
            src = W_leaf + (size_t)e * DD * DD;
            dst = WlT + (size_t)e * DD * DD;
            tl = (bid - 64) & 63;
        }
        int tr = tl >> 3, tc = tl & 7;
        #pragma unroll
        for (int j = 0; j < 16; j++) {
            int i2 = t + j * 256; int r = i2 >> 6, c = i2 & 63;
            tile[r][c] = f2bf(src[(size_t)(tr * 64 + r) * DD + tc * 64 + c]);
        }
        __syncthreads();
        #pragma unroll
        for (int j = 0; j < 16; j++) {
            int i2 = t + j * 256; int r = i2 >> 6, c = i2 & 63;
            dst[(size_t)(tc * 64 + r) * DD + tr * 64 + c] = tile[c][r];
        }
    } else if (bid < 832) {
        int idx = (bid - 576) * 256 + t;           // 65536: WldT [e][16][512]
        int e = idx >> 13, rem = idx & 8191;
        int o = rem >> 9, k = rem & 511;
        unsigned short v = 0;
        if (o < 8) v = f2bf(W_ldec[((size_t)e * DD + k) * EE + o]);
        WldT[idx] = v;
    } else {
        int idx = (bid - 832) * 256 + t;           // 8192: WdT [16][512]
        int o = idx >> 9, k = idx & 511;
        WdT[idx] = (o < 8) ? f2bf(W_dec[(size_t)k * EE + o]) : (unsigned short)0;
    }
}

// ---------- K1: bf16 MFMA root GEMM; BM=256, 512 threads, dbuf single-barrier K-loop ----------
__global__ __launch_bounds__(512) void k_root(
    const float* __restrict__ x,
    const unsigned short* __restrict__ WrTh,
    const float* __restrict__ b_root,
    const unsigned short* __restrict__ WdT,
    unsigned short* __restrict__ hbuf,
    float* __restrict__ logit_part)          // [4][65536][8], p = cb
{
    __shared__ unsigned short smem[40960];       // 81920 B; A dbuf 2x32KB + B dbuf 2x8KB; epi lh[256][136]
    float* fA = (float*)&smem[0];                // f32 buffers at idx 0 / 8192 (256x32 f32 each)
    unsigned short* bB = &smem[32768];           // u16 buffers at idx 0 / 4096 (128x32 bf16 each)

    int bid = blockIdx.x;                         // 1024 = 256 mb * 4 cb
    int mb = (bid >> 5) * 8 + (bid & 7);          // XCD-swizzled
    int cb = (bid >> 3) & 3;
    int m0 = mb * 256, n0 = cb * 128;

    int t = threadIdx.x;
    int wid = t >> 6, lane = t & 63;
    int wr = wid >> 1, wc = wid & 1;              // wr 0..3, wc 0..1
    int l15 = lane & 15, l4 = lane >> 4;

    int arow = t >> 3;                            // 0..63
    int aswz = ((t & 7) ^ (arow & 7)) * 4;
    const float* srcA = x + (size_t)(m0 + arow) * DD + aswz;
    int adst = arow * 32 + aswz;
    const unsigned short* srcB = WrTh + (size_t)(n0 + (t >> 2)) * DD + (t & 3) * 8;

    f32x4 acc[4][4];
    #pragma unroll
    for (int m = 0; m < 4; m++)
        #pragma unroll
        for (int n = 0; n < 4; n++) acc[m][n] = (f32x4){0.f, 0.f, 0.f, 0.f};

    #pragma unroll
    for (int j = 0; j < 4; j++)
        gload_lds16(srcA + (size_t)j * 64 * DD, fA + adst + j * 2048);
    gload_lds16(srcB, bB + t * 8);
    __syncthreads();

    for (int it = 0; it < 16; ++it) {
        int cur = it & 1;
        int ao = cur * 8192;
        int bo = cur * 4096;
        if (it < 15) {
            int k0n = (it + 1) * 32;
            int aon = (cur ^ 1) * 8192, bon = (cur ^ 1) * 4096;
            #pragma unroll
            for (int j = 0; j < 4; j++)
                gload_lds16(srcA + (size_t)j * 64 * DD + k0n, fA + aon + adst + j * 2048);
            gload_lds16(srcB + k0n, bB + bon + t * 8);
        }
        bf16x8 fa[4], fb[4];
        #pragma unroll
        for (int m = 0; m < 4; m++) {
            int r = wr * 64 + m * 16 + l15;
            int s0 = (l4 * 2) ^ (r & 7), s1 = (l4 * 2 + 1) ^ (r & 7);
            f32x4 lo = *(const f32x4*)&fA[ao + r * 32 + s0 * 4];
            f32x4 hi = *(const f32x4*)&fA[ao + r * 32 + s1 * 4];
            #pragma unroll
            for (int j = 0; j < 4; j++) { fa[m][j] = (__bf16)lo[j]; fa[m][4 + j] = (__bf16)hi[j]; }
        }
        #pragma unroll
        for (int n = 0; n < 4; n++)
            fb[n] = *(const bf16x8*)&bB[bo + (wc * 64 + n * 16 + l15) * 32 + l4 * 8];
        #pragma unroll
        for (int m = 0; m < 4; m++)
            #pragma unroll
            for (int n = 0; n < 4; n++)
                acc[m][n] = mfma_bf16(fa[m], fb[n], acc[m][n]);
        __syncthreads();
    }

    float bcol[4];
    #pragma unroll
    for (int n = 0; n < 4; n++) bcol[n] = b_root[n0 + wc * 64 + n * 16 + l15];
    #pragma unroll
    for (int n = 0; n < 4; n++) {
        int coll = wc * 64 + n * 16 + l15;
        #pragma unroll
        for (int m = 0; m < 4; m++) {
            int rl = wr * 64 + m * 16 + l4 * 4;
            #pragma unroll
            for (int i = 0; i < 4; i++) {
                float v = acc[m][n][i] + bcol[n];
                v = v > 0.f ? v : 0.f;
                smem[(rl + i) * 136 + coll] = f2bf(v);
            }
        }
    }
    __syncthreads();

    {
        int r = t >> 1, c0s = (t & 1) * 64;
        unsigned short* dst = hbuf + (size_t)(m0 + r) * DD + n0 + c0s;
        #pragma unroll
        for (int j = 0; j < 8; j++)
            *(u16x8*)(dst + j * 8) = *(const u16x8*)&smem[r * 136 + c0s + j * 8];
    }

    f32x4 acc2[2];
    acc2[0] = (f32x4){0.f, 0.f, 0.f, 0.f};
    acc2[1] = (f32x4){0.f, 0.f, 0.f, 0.f};
    #pragma unroll
    for (int kk = 0; kk < 4; kk++) {
        bf16x8 bb = *(const bf16x8*)(WdT + (size_t)l15 * DD + n0 + kk * 32 + l4 * 8);
        #pragma unroll
        for (int m2 = 0; m2 < 2; m2++) {
            bf16x8 aa = *(const bf16x8*)&smem[(wid * 32 + m2 * 16 + l15) * 136 + kk * 32 + l4 * 8];
            acc2[m2] = mfma_bf16(aa, bb, acc2[m2]);
        }
    }
    if (l15 < 8) {
        #pragma unroll
        for (int m2 = 0; m2 < 2; m2++)
            #pragma unroll
            for (int i = 0; i < 4; i++) {
                int rowg = m0 + wid * 32 + m2 * 16 + l4 * 4 + i;
                logit_part[((size_t)cb * 65536 + rowg) * 8 + l15] = acc2[m2][i];
            }
    }
}

// ---------- K2: dec softmax + route + gap-flag + fused ballot count ----------
__global__ __launch_bounds__(256) void k_dec(
    const float* __restrict__ logit_part,
    const float* __restrict__ b_dec,
    float* __restrict__ out,
    int* __restrict__ route,
    int* __restrict__ meta,
    int* __restrict__ rescue_list)
{
    __shared__ int wcnt[4][8];
    int b = blockIdx.x * 256 + threadIdx.x;
    double lg[8];
    #pragma unroll
    for (int o = 0; o < 8; o++) lg[o] = (double)b_dec[o];
    #pragma unroll
    for (int ppp = 0; ppp < 4; ppp++) {
        #pragma unroll
        for (int o = 0; o < 8; o++)
            lg[o] += (double)logit_part[((size_t)ppp * 65536 + b) * 8 + o];
    }
    double mx = -1e300, mx2 = -1e300; int idx = 0;
    #pragma unroll
    for (int o = 0; o < 8; o++) {
        if (lg[o] > mx) { mx2 = mx; mx = lg[o]; idx = o; }
        else if (lg[o] > mx2) mx2 = lg[o];
    }
    float ev[8], s = 0.f;
    #pragma unroll
    for (int o = 0; o < 8; o++) { ev[o] = expf((float)(lg[o] - mx)); s += ev[o]; }
    float inv = 1.f / s;
    float4 o0, o1;
    o0.x = ev[0]*inv; o0.y = ev[1]*inv; o0.z = ev[2]*inv; o0.w = ev[3]*inv;
    o1.x = ev[4]*inv; o1.y = ev[5]*inv; o1.z = ev[6]*inv; o1.w = ev[7]*inv;
    float4* op = (float4*)(out + (size_t)b * 16);
    op[0] = o0; op[1] = o1;
    route[b] = idx;
    if (mx - mx2 < 3e-3) {
        int pos = atomicAdd(&meta[27], 1);
        if (pos < 8192) rescue_list[pos] = b;
    }
    int lane = threadIdx.x & 63, wv = threadIdx.x >> 6;
    #pragma unroll
    for (int ex = 0; ex < 8; ex++) {
        unsigned long long m = __ballot(idx == ex);
        if (lane == 0) wcnt[wv][ex] = __popcll(m);
    }
    __syncthreads();
    if (threadIdx.x < 8) {
        int ex = threadIdx.x;
        atomicAdd(&meta[ex], wcnt[0][ex] + wcnt[1][ex] + wcnt[2][ex] + wcnt[3][ex]);
    }
}

// ---------- K2b: exact f64 rescue (dec + route + count fixup) ----------
__global__ __launch_bounds__(256) void k_rescue(
    const float* __restrict__ x,
    const float* __restrict__ W_root,
    const float* __restrict__ b_root,
    const float* __restrict__ W_dec,
    const float* __restrict__ b_dec,
    const int* __restrict__ rescue_list,
    int* __restrict__ meta,
    float* __restrict__ out,
    int* __restrict__ route)
{
    int nresc = min(meta[27], 8192);
    if ((int)blockIdx.x >= nresc) return;
    int row = rescue_list[blockIdx.x];
    int t = threadIdx.x;

    __shared__ float xr[512];
    __shared__ double red[4][8];
    xr[t * 2]     = x[(size_t)row * DD + t * 2];
    xr[t * 2 + 1] = x[(size_t)row * DD + t * 2 + 1];
    __syncthreads();

    int d0 = t, d1 = t + 256;
    double a0 = 0.0, a1 = 0.0;
    for (int k = 0; k < DD; k++) {
        double xv = (double)xr[k];
        a0 += xv * (double)W_root[(size_t)k * DD + d0];
        a1 += xv * (double)W_root[(size_t)k * DD + d1];
    }
    double h0 = fmax(a0 + (double)b_root[d0], 0.0);
    double h1 = fmax(a1 + (double)b_root[d1], 0.0);
    double so[8];
    #pragma unroll
    for (int o = 0; o < 8; o++)
        so[o] = h0 * (double)W_dec[d0 * 8 + o] + h1 * (double)W_dec[d1 * 8 + o];
    #pragma unroll
    for (int d = 1; d < 64; d <<= 1)
        #pragma unroll
        for (int o = 0; o < 8; o++) so[o] += __shfl_xor(so[o], d, 64);
    if ((t & 63) == 0) {
        #pragma unroll
        for (int o = 0; o < 8; o++) red[t >> 6][o] = so[o];
    }
    __syncthreads();
    if (t == 0) {
        double lg[8]; double mx = -1e300; int idx = 0;
        #pragma unroll
        for (int o = 0; o < 8; o++) {
            lg[o] = red[0][o] + red[1][o] + red[2][o] + red[3][o] + (double)b_dec[o];
            if (lg[o] > mx) { mx = lg[o]; idx = o; }
        }
        double ev[8], s = 0.0;
        #pragma unroll
        for (int o = 0; o < 8; o++) { ev[o] = exp(lg[o] - mx); s += ev[o]; }
        double inv = 1.0 / s;
        float4 o0, o1;
        o0.x = (float)(ev[0]*inv); o0.y = (float)(ev[1]*inv);
        o0.z = (float)(ev[2]*inv); o0.w = (float)(ev[3]*inv);
        o1.x = (float)(ev[4]*inv); o1.y = (float)(ev[5]*inv);
        o1.z = (float)(ev[6]*inv); o1.w = (float)(ev[7]*inv);
        float4* op = (float4*)(out + (size_t)row * 16);
        op[0] = o0; op[1] = o1;
        int old = route[row];
        if (idx != old) {
            atomicSub(&meta[old], 1);
            atomicAdd(&meta[idx], 1);
            route[row] = idx;
        }
    }
}

// ---------- K3: scan (256-row padding) ----------
__global__ void k_scan(int* __restrict__ meta)
{
    if (threadIdx.x == 0 && blockIdx.x == 0) {
        int run = 0, rb = 0;
        for (int e = 0; e < 8; e++) {
            int c = meta[e];
            meta[16 + e] = run;
            meta[8 + e]  = run;
            int n = (c + 255) >> 8;
            for (int j = 0; j < n; j++) meta[32 + rb + j] = e | (j << 8);
            rb += n;
            run += n << 8;
        }
        meta[24] = rb;
    }
}

// ---------- K4: scatter — ballot-ranked, 8 atomics/block ----------
__global__ __launch_bounds__(256) void k_scatter(
    const int* __restrict__ route, int* __restrict__ meta, int* __restrict__ rows_list)
{
    __shared__ int wcnt[4][8];
    __shared__ int wbase[4][8];
    int b = blockIdx.x * 256 + threadIdx.x;
    int e = route[b];
    int lane = threadIdx.x & 63, wv = threadIdx.x >> 6;
    unsigned long long mymask = 0;
    #pragma unroll
    for (int ex = 0; ex < 8; ex++) {
        unsigned long long m = __ballot(e == ex);
        if (e == ex) mymask = m;
        if (lane == 0) wcnt[wv][ex] = __popcll(m);
    }
    int myrank = __popcll(mymask & ((1ULL << lane) - 1ULL));
    __syncthreads();
    if (threadIdx.x < 8) {
        int ex = threadIdx.x;
        int c0 = wcnt[0][ex], c1 = wcnt[1][ex], c2 = wcnt[2][ex], c3 = wcnt[3][ex];
        int base = atomicAdd(&meta[8 + ex], c0 + c1 + c2 + c3);
        wbase[0][ex] = base;
        wbase[1][ex] = base + c0;
        wbase[2][ex] = base + c0 + c1;
        wbase[3][ex] = base + c0 + c1 + c2;
    }
    __syncthreads();
    rows_list[wbase[wv][e] + myrank] = b;
}

// ---------- K5: grouped leaf GEMM; BM=256, 512 threads, dbuf single-barrier K-loop ----------
__global__ __launch_bounds__(512) void k_gemm2(
    const unsigned short* __restrict__ hbuf,
    const unsigned short* __restrict__ WlT,
    const float* __restrict__ b_leaf,
    const unsigned short* __restrict__ WldT,
    const int* __restrict__ rows_list,
    const int* __restrict__ meta,
    float* __restrict__ ldec_part)           // [4][65536][8]
{
    __shared__ unsigned short smem[34816];       // 69632 B; loop: A dbuf 2x16KB + B dbuf 2x8KB; epi lh[256][136]
    // A buffers: u16 idx 0 / 8192 (256x32 each); B buffers: u16 idx 16384 / 20480 (128x32 each)

    int bid = blockIdx.x;                        // 1088 = 272 rb * 4 cb (swizzled)
    int rbid = (bid >> 5) * 8 + (bid & 7);
    int cb = (bid >> 3) & 3;
    if (rbid >= meta[24]) return;
    int pk = meta[32 + rbid];
    int e = pk & 255, lrb = pk >> 8;
    int poff_e = meta[16 + e], cnt_e = meta[e];
    int n0 = cb * 128;

    int t = threadIdx.x;
    int wid = t >> 6, lane = t & 63;
    int wr = wid >> 1, wc = wid & 1;             // wr 0..3, wc 0..1
    int l15 = lane & 15, l4 = lane >> 4;

    int slot0 = poff_e + lrb * 256 + (t >> 2);
    int slot1 = slot0 + 128;
    int lastv = poff_e + cnt_e - 1;
    int grow0 = rows_list[min(slot0, lastv)];    // clamp pad slots (idempotent recompute)
    int grow1 = rows_list[min(slot1, lastv)];
    const unsigned short* srcA0 = hbuf + (size_t)grow0 * DD + (t & 3) * 8;
    const unsigned short* srcA1 = hbuf + (size_t)grow1 * DD + (t & 3) * 8;
    const unsigned short* srcB  = WlT + (size_t)e * DD * DD + (size_t)(n0 + (t >> 2)) * DD + (t & 3) * 8;

    f32x4 acc[4][4];
    #pragma unroll
    for (int m = 0; m < 4; m++)
        #pragma unroll
        for (int n = 0; n < 4; n++) acc[m][n] = (f32x4){0.f, 0.f, 0.f, 0.f};

    // prologue: stage tile 0 into buffer 0
    gload_lds16(srcA0, &smem[t * 8]);
    gload_lds16(srcA1, &smem[4096 + t * 8]);
    gload_lds16(srcB,  &smem[16384 + t * 8]);
    __syncthreads();

    for (int it = 0; it < 16; ++it) {
        int cur = it & 1;
        int ao = cur * 8192, bo = 16384 + cur * 4096;
        if (it < 15) {
            int k0n = (it + 1) * 32;
            int aon = (cur ^ 1) * 8192, bon = 16384 + (cur ^ 1) * 4096;
            gload_lds16(srcA0 + k0n, &smem[aon + t * 8]);
            gload_lds16(srcA1 + k0n, &smem[aon + 4096 + t * 8]);
            gload_lds16(srcB + k0n,  &smem[bon + t * 8]);
        }
        bf16x8 af[4], bfr[4];
        #pragma unroll
        for (int m = 0; m < 4; m++)
            af[m] = *(const bf16x8*)&smem[ao + (wr * 64 + m * 16 + l15) * 32 + l4 * 8];
        #pragma unroll
        for (int n = 0; n < 4; n++)
            bfr[n] = *(const bf16x8*)&smem[bo + (wc * 64 + n * 16 + l15) * 32 + l4 * 8];
        #pragma unroll
        for (int m = 0; m < 4; m++)
            #pragma unroll
            for (int n = 0; n < 4; n++)
                acc[m][n] = mfma_bf16(af[m], bfr[n], acc[m][n]);
        __syncthreads();
    }

    // epilogue 1: bias + relu -> lh tile (bf16) in smem [256][136]
    float bcol[4];
    #pragma unroll
    for (int n = 0; n < 4; n++) bcol[n] = b_leaf[(size_t)e * DD + n0 + wc * 64 + n * 16 + l15];
    #pragma unroll
    for (int n = 0; n < 4; n++) {
        int coll = wc * 64 + n * 16 + l15;
        #pragma unroll
        for (int m = 0; m < 4; m++) {
            int rl = wr * 64 + m * 16 + l4 * 4;
            #pragma unroll
            for (int i = 0; i < 4; i++) {
                float v = acc[m][n][i] + bcol[n];
                v = v > 0.f ? v : 0.f;
                smem[(rl + i) * 136 + coll] = f2bf(v);
            }
        }
    }
    __syncthreads();

    // epilogue 2: ldec partial = lh_tile @ W_ldec[e][n0:n0+128][:] via MFMA (8 waves x 32 rows)
    f32x4 acc2[2];
    acc2[0] = (f32x4){0.f, 0.f, 0.f, 0.f};
    acc2[1] = (f32x4){0.f, 0.f, 0.f, 0.f};
    #pragma unroll
    for (int kk = 0; kk < 4; kk++) {
        bf16x8 bb = *(const bf16x8*)(WldT + ((size_t)e * 16 + l15) * DD + n0 + kk * 32 + l4 * 8);
        #pragma unroll
        for (int m2 = 0; m2 < 2; m2++) {
            bf16x8 aa = *(const bf16x8*)&smem[(wid * 32 + m2 * 16 + l15) * 136 + kk * 32 + l4 * 8];
            acc2[m2] = mfma_bf16(aa, bb, acc2[m2]);
        }
    }
    if (l15 < 8) {
        #pragma unroll
        for (int m2 = 0; m2 < 2; m2++)
            #pragma unroll
            for (int i = 0; i < 4; i++) {
                int rl = wid * 32 + m2 * 16 + l4 * 4 + i;
                int s = min(poff_e + lrb * 256 + rl, lastv);
                int brow = rows_list[s];             // pad slots: duplicate identical writes
                ldec_part[((size_t)cb * 65536 + brow) * 8 + l15] = acc2[m2][i];
            }
    }
}

// ---------- K6: sel softmax ----------
__global__ __launch_bounds__(256) void k_sel(
    const float* __restrict__ ldec_part,
    const int* __restrict__ route,
    const float* __restrict__ b_ldec,
    float* __restrict__ out)
{
    int b = blockIdx.x * 256 + threadIdx.x;
    int e = route[b];
    float lg[8];
    #pragma unroll
    for (int o = 0; o < 8; o++) lg[o] = b_ldec[e * 8 + o];
    #pragma unroll
    for (int p = 0; p < 4; p++) {
        const float4* ap = (const float4*)(ldec_part + ((size_t)p * 65536 + b) * 8);
        float4 a0 = ap[0], a1 = ap[1];
        lg[0]+=a0.x; lg[1]+=a0.y; lg[2]+=a0.z; lg[3]+=a0.w;
        lg[4]+=a1.x; lg[5]+=a1.y; lg[6]+=a1.z; lg[7]+=a1.w;
    }
    float mx = -1e30f;
    #pragma unroll
    for (int o = 0; o < 8; o++) mx = fmaxf(mx, lg[o]);
    float ev[8], s = 0.f;
    #pragma unroll
    for (int o = 0; o < 8; o++) { ev[o] = expf(lg[o] - mx); s += ev[o]; }
    float inv = 1.f / s;
    float4 o0, o1;
    o0.x = ev[0]*inv; o0.y = ev[1]*inv; o0.z = ev[2]*inv; o0.w = ev[3]*inv;
    o1.x = ev[4]*inv; o1.y = ev[5]*inv; o1.z = ev[6]*inv; o1.w = ev[7]*inv;
    float4* op = (float4*)(out + (size_t)b * 16 + 8);
    op[0] = o0; op[1] = o1;
}

extern "C" void kernel_launch(void* const* d_in, const int* in_sizes, int n_in,
                              void* d_out, int out_size, void* d_ws, size_t ws_size,
                              hipStream_t stream)
{
    const float* x      = (const float*)d_in[0];
    const float* W_root = (const float*)d_in[1];
    const float* b_root = (const float*)d_in[2];
    const float* W_dec  = (const float*)d_in[3];
    const float* b_dec  = (const float*)d_in[4];
    const float* W_leaf = (const float*)d_in[5];
    const float* b_leaf = (const float*)d_in[6];
    const float* W_ldec = (const float*)d_in[7];
    const float* b_ldec = (const float*)d_in[8];
    float* out = (float*)d_out;

    char* w = (char*)d_ws;
    unsigned short* hbuf       = (unsigned short*)(w);               // 67,108,864
    float*          logit_part = (float*)(w + 67108864);             //  8,388,608
    unsigned short* WlT        = (unsigned short*)(w + 75497472);    //  4,194,304
    unsigned short* WldT       = (unsigned short*)(w + 79691776);    //    131,072
    unsigned short* WdT        = (unsigned short*)(w + 79822848);    //     16,384
    float*          ldec_part  = (float*)(w + 79839232);             //  8,388,608
    int*            route      = (int*)(w + 88227840);               //    262,144
    int*            rows_list  = (int*)(w + 88489984);               //    273,408 (68352 ints; 256-pad bound 67576)
    unsigned short* WrTh       = (unsigned short*)(w + 88763392);    //    524,288
    int*            rescue     = (int*)(w + 89287680);               //     32,768
    int*            meta       = (int*)(w + 89320448);               //      4,096
    const size_t WS_NEED = 89324544ULL;
    if (ws_size < WS_NEED) return;

    (void)hipMemsetAsync(meta, 0, 4096, stream);

    k_prep   <<<864,  256, 0, stream>>>(W_root, W_leaf, W_ldec, W_dec, WrTh, WlT, WldT, WdT);
    k_root   <<<1024, 512, 0, stream>>>(x, WrTh, b_root, WdT, hbuf, logit_part);
    k_dec    <<<256,  256, 0, stream>>>(logit_part, b_dec, out, route, meta, rescue);
    k_rescue <<<8192, 256, 0, stream>>>(x, W_root, b_root, W_dec, b_dec, rescue, meta, out, route);
    k_scan   <<<1,    64,  0, stream>>>(meta);
    k_scatter<<<256,  256, 0, stream>>>(route, meta, rows_list);
    k_gemm2  <<<1088, 512, 0, stream>>>(hbuf, WlT, b_leaf, WldT, rows_list, meta, ldec_part);
    k_sel    <<<256,  256, 0, stream>>>(ldec_part, route, b_ldec, out);
}

// Round 19
// 244.193 us; speedup vs baseline: 1.0155x; 1.0155x over previous
//
#include <hip/hip_runtime.h>
#include <stdint.h>

#define DD   512
#define EE   8

typedef __bf16 bf16x8 __attribute__((ext_vector_type(8)));
typedef float  f32x4  __attribute__((ext_vector_type(4)));
typedef unsigned short u16x8 __attribute__((ext_vector_type(8)));

__device__ __forceinline__ unsigned short f2bf(float f) {  // RTNE
    union { float f; unsigned int i; } v; v.f = f;
    unsigned int x = v.i;
    x += 0x7fffu + ((x >> 16) & 1u);
    return (unsigned short)(x >> 16);
}
__device__ __forceinline__ void gload_lds16(const void* g, void* l) {
    __builtin_amdgcn_global_load_lds(
        (const __attribute__((address_space(1))) unsigned int*)g,
        (__attribute__((address_space(3))) unsigned int*)l, 16, 0, 0);
}
__device__ __forceinline__ f32x4 mfma_bf16(bf16x8 a, bf16x8 b, f32x4 c) {
    return __builtin_amdgcn_mfma_f32_16x16x32_bf16(a, b, c, 0, 0, 0);
}

// ---------- K0: merged prep — W_root^T, W_leaf^T, W_ldec pad^T, W_dec pad^T ----------
__global__ __launch_bounds__(256) void k_prep(
    const float* __restrict__ W_root, const float* __restrict__ W_leaf,
    const float* __restrict__ W_ldec, const float* __restrict__ W_dec,
    unsigned short* __restrict__ WrTh, unsigned short* __restrict__ WlT,
    unsigned short* __restrict__ WldT, unsigned short* __restrict__ WdT)
{
    __shared__ unsigned short tile[64][65];
    int bid = blockIdx.x;            // 864 = 64 (wtr) + 512 (trW) + 256 (trpad) + 32 (trdec)
    int t = threadIdx.x;
    if (bid < 576) {
        const float* src;
        unsigned short* dst;
        int tl;
        if (bid < 64) {
            src = W_root; dst = WrTh; tl = bid;
        } else {
            int e = (bid - 64) >> 6;
            src = W_leaf + (size_t)e * DD * DD;
            dst = WlT + (size_t)e * DD * DD;
            tl = (bid - 64) & 63;
        }
        int tr = tl >> 3, tc = tl & 7;
        #pragma unroll
        for (int j = 0; j < 16; j++) {
            int i2 = t + j * 256; int r = i2 >> 6, c = i2 & 63;
            tile[r][c] = f2bf(src[(size_t)(tr * 64 + r) * DD + tc * 64 + c]);
        }
        __syncthreads();
        #pragma unroll
        for (int j = 0; j < 16; j++) {
            int i2 = t + j * 256; int r = i2 >> 6, c = i2 & 63;
            dst[(size_t)(tc * 64 + r) * DD + tr * 64 + c] = tile[c][r];
        }
    } else if (bid < 832) {
        int idx = (bid - 576) * 256 + t;           // 65536: WldT [e][16][512]
        int e = idx >> 13, rem = idx & 8191;
        int o = rem >> 9, k = rem & 511;
        unsigned short v = 0;
        if (o < 8) v = f2bf(W_ldec[((size_t)e * DD + k) * EE + o]);
        WldT[idx] = v;
    } else {
        int idx = (bid - 832) * 256 + t;           // 8192: WdT [16][512]
        int o = idx >> 9, k = idx & 511;
        WdT[idx] = (o < 8) ? f2bf(W_dec[(size_t)k * EE + o]) : (unsigned short)0;
    }
}

// ---------- K1: bf16 MFMA root GEMM; BM=256, 512 threads; counted-vmcnt dbuf K-loop ----------
// A staged f32 via global_load_lds (pre-swizzled source); cvt at fragment read. B bf16 linear.
// Raw s_barrier + s_waitcnt vmcnt(N): prefetch batches never drained at birth.
__global__ __launch_bounds__(512) void k_root(
    const float* __restrict__ x,
    const unsigned short* __restrict__ WrTh,
    const float* __restrict__ b_root,
    const unsigned short* __restrict__ WdT,
    unsigned short* __restrict__ hbuf,
    float* __restrict__ logit_part)          // [4][65536][8], p = cb
{
    __shared__ unsigned short smem[40960];       // 81920 B; A dbuf 2x32KB + B dbuf 2x8KB; epi lh[256][136]
    float* fA = (float*)&smem[0];                // f32 buffers at idx 0 / 8192 (256x32 f32 each)
    unsigned short* bB = &smem[32768];           // u16 buffers at idx 0 / 4096 (128x32 bf16 each)

    int bid = blockIdx.x;                         // 1024 = 256 mb * 4 cb
    int mb = (bid >> 5) * 8 + (bid & 7);          // XCD-swizzled
    int cb = (bid >> 3) & 3;
    int m0 = mb * 256, n0 = cb * 128;

    int t = threadIdx.x;
    int wid = t >> 6, lane = t & 63;
    int wr = wid >> 1, wc = wid & 1;              // wr 0..3, wc 0..1
    int l15 = lane & 15, l4 = lane >> 4;

    int arow = t >> 3;                            // 0..63
    int aswz = ((t & 7) ^ (arow & 7)) * 4;
    const float* srcA = x + (size_t)(m0 + arow) * DD + aswz;
    int adst = arow * 32 + aswz;
    const unsigned short* srcB = WrTh + (size_t)(n0 + (t >> 2)) * DD + (t & 3) * 8;

    f32x4 acc[4][4];
    #pragma unroll
    for (int m = 0; m < 4; m++)
        #pragma unroll
        for (int n = 0; n < 4; n++) acc[m][n] = (f32x4){0.f, 0.f, 0.f, 0.f};

    // prologue: stage tiles 0 (buf0) and 1 (buf1); 5 loads each
    #pragma unroll
    for (int j = 0; j < 4; j++)
        gload_lds16(srcA + (size_t)j * 64 * DD, fA + adst + j * 2048);
    gload_lds16(srcB, bB + t * 8);
    #pragma unroll
    for (int j = 0; j < 4; j++)
        gload_lds16(srcA + (size_t)j * 64 * DD + 32, fA + 8192 + adst + j * 2048);
    gload_lds16(srcB + 32, bB + 4096 + t * 8);
    asm volatile("s_waitcnt vmcnt(5)" ::: "memory");   // tile0 landed (only tile1's 5 remain)
    __builtin_amdgcn_sched_barrier(0);
    __builtin_amdgcn_s_barrier();
    __builtin_amdgcn_sched_barrier(0);

    for (int it = 0; it < 16; ++it) {
        int cur = it & 1;
        int ao = cur * 8192, bo = cur * 4096;

        // compute tile it from buf[cur]
        bf16x8 fa[4], fb[4];
        #pragma unroll
        for (int m = 0; m < 4; m++) {
            int r = wr * 64 + m * 16 + l15;
            int s0 = (l4 * 2) ^ (r & 7), s1 = (l4 * 2 + 1) ^ (r & 7);
            f32x4 lo = *(const f32x4*)&fA[ao + r * 32 + s0 * 4];
            f32x4 hi = *(const f32x4*)&fA[ao + r * 32 + s1 * 4];
            #pragma unroll
            for (int j = 0; j < 4; j++) { fa[m][j] = (__bf16)lo[j]; fa[m][4 + j] = (__bf16)hi[j]; }
        }
        #pragma unroll
        for (int n = 0; n < 4; n++)
            fb[n] = *(const bf16x8*)&bB[bo + (wc * 64 + n * 16 + l15) * 32 + l4 * 8];
        #pragma unroll
        for (int m = 0; m < 4; m++)
            #pragma unroll
            for (int n = 0; n < 4; n++)
                acc[m][n] = mfma_bf16(fa[m], fb[n], acc[m][n]);

        if (it == 15) break;

        __builtin_amdgcn_s_barrier();            // all waves done reading buf[cur]
        __builtin_amdgcn_sched_barrier(0);
        if (it < 14) {                           // stage tile it+2 into buf[cur]
            int k0n = (it + 2) * 32;
            #pragma unroll
            for (int j = 0; j < 4; j++)
                gload_lds16(srcA + (size_t)j * 64 * DD + k0n, fA + ao + adst + j * 2048);
            gload_lds16(srcB + k0n, bB + bo + t * 8);
            asm volatile("s_waitcnt vmcnt(5)" ::: "memory");   // tile it+1 landed
        } else {
            asm volatile("s_waitcnt vmcnt(0)" ::: "memory");   // tile 15 landed
        }
        __builtin_amdgcn_sched_barrier(0);
        __builtin_amdgcn_s_barrier();            // all waves: next buffer ready
        __builtin_amdgcn_sched_barrier(0);
    }
    __syncthreads();                             // full drain before smem reuse

    // epilogue 1: bias + relu -> h tile (bf16) in smem as lh[256][136]
    float bcol[4];
    #pragma unroll
    for (int n = 0; n < 4; n++) bcol[n] = b_root[n0 + wc * 64 + n * 16 + l15];
    #pragma unroll
    for (int n = 0; n < 4; n++) {
        int coll = wc * 64 + n * 16 + l15;
        #pragma unroll
        for (int m = 0; m < 4; m++) {
            int rl = wr * 64 + m * 16 + l4 * 4;
            #pragma unroll
            for (int i = 0; i < 4; i++) {
                float v = acc[m][n][i] + bcol[n];
                v = v > 0.f ? v : 0.f;
                smem[(rl + i) * 136 + coll] = f2bf(v);
            }
        }
    }
    __syncthreads();

    // epilogue 2a: vectorized h store from lh (256 rows x 128 cols)
    {
        int r = t >> 1, c0s = (t & 1) * 64;
        unsigned short* dst = hbuf + (size_t)(m0 + r) * DD + n0 + c0s;
        #pragma unroll
        for (int j = 0; j < 8; j++)
            *(u16x8*)(dst + j * 8) = *(const u16x8*)&smem[r * 136 + c0s + j * 8];
    }

    // epilogue 2b: logit partial = lh_tile @ W_dec[n0:n0+128][:] via MFMA (8 waves x 32 rows)
    f32x4 acc2[2];
    acc2[0] = (f32x4){0.f, 0.f, 0.f, 0.f};
    acc2[1] = (f32x4){0.f, 0.f, 0.f, 0.f};
    #pragma unroll
    for (int kk = 0; kk < 4; kk++) {
        bf16x8 bb = *(const bf16x8*)(WdT + (size_t)l15 * DD + n0 + kk * 32 + l4 * 8);
        #pragma unroll
        for (int m2 = 0; m2 < 2; m2++) {
            bf16x8 aa = *(const bf16x8*)&smem[(wid * 32 + m2 * 16 + l15) * 136 + kk * 32 + l4 * 8];
            acc2[m2] = mfma_bf16(aa, bb, acc2[m2]);
        }
    }
    if (l15 < 8) {
        #pragma unroll
        for (int m2 = 0; m2 < 2; m2++)
            #pragma unroll
            for (int i = 0; i < 4; i++) {
                int rowg = m0 + wid * 32 + m2 * 16 + l4 * 4 + i;
                logit_part[((size_t)cb * 65536 + rowg) * 8 + l15] = acc2[m2][i];
            }
    }
}

// ---------- K2: dec softmax + route + gap-flag + fused ballot count ----------
__global__ __launch_bounds__(256) void k_dec(
    const float* __restrict__ logit_part,
    const float* __restrict__ b_dec,
    float* __restrict__ out,
    int* __restrict__ route,
    int* __restrict__ meta,
    int* __restrict__ rescue_list)
{
    __shared__ int wcnt[4][8];
    int b = blockIdx.x * 256 + threadIdx.x;
    double lg[8];
    #pragma unroll
    for (int o = 0; o < 8; o++) lg[o] = (double)b_dec[o];
    #pragma unroll
    for (int ppp = 0; ppp < 4; ppp++) {
        #pragma unroll
        for (int o = 0; o < 8; o++)
            lg[o] += (double)logit_part[((size_t)ppp * 65536 + b) * 8 + o];
    }
    double mx = -1e300, mx2 = -1e300; int idx = 0;
    #pragma unroll
    for (int o = 0; o < 8; o++) {
        if (lg[o] > mx) { mx2 = mx; mx = lg[o]; idx = o; }
        else if (lg[o] > mx2) mx2 = lg[o];
    }
    float ev[8], s = 0.f;
    #pragma unroll
    for (int o = 0; o < 8; o++) { ev[o] = expf((float)(lg[o] - mx)); s += ev[o]; }
    float inv = 1.f / s;
    float4 o0, o1;
    o0.x = ev[0]*inv; o0.y = ev[1]*inv; o0.z = ev[2]*inv; o0.w = ev[3]*inv;
    o1.x = ev[4]*inv; o1.y = ev[5]*inv; o1.z = ev[6]*inv; o1.w = ev[7]*inv;
    float4* op = (float4*)(out + (size_t)b * 16);
    op[0] = o0; op[1] = o1;
    route[b] = idx;
    if (mx - mx2 < 3e-3) {
        int pos = atomicAdd(&meta[27], 1);
        if (pos < 8192) rescue_list[pos] = b;
    }
    int lane = threadIdx.x & 63, wv = threadIdx.x >> 6;
    #pragma unroll
    for (int ex = 0; ex < 8; ex++) {
        unsigned long long m = __ballot(idx == ex);
        if (lane == 0) wcnt[wv][ex] = __popcll(m);
    }
    __syncthreads();
    if (threadIdx.x < 8) {
        int ex = threadIdx.x;
        atomicAdd(&meta[ex], wcnt[0][ex] + wcnt[1][ex] + wcnt[2][ex] + wcnt[3][ex]);
    }
}

// ---------- K2b: exact f64 rescue (dec + route + count fixup) ----------
__global__ __launch_bounds__(256) void k_rescue(
    const float* __restrict__ x,
    const float* __restrict__ W_root,
    const float* __restrict__ b_root,
    const float* __restrict__ W_dec,
    const float* __restrict__ b_dec,
    const int* __restrict__ rescue_list,
    int* __restrict__ meta,
    float* __restrict__ out,
    int* __restrict__ route)
{
    int nresc = min(meta[27], 8192);
    if ((int)blockIdx.x >= nresc) return;
    int row = rescue_list[blockIdx.x];
    int t = threadIdx.x;

    __shared__ float xr[512];
    __shared__ double red[4][8];
    xr[t * 2]     = x[(size_t)row * DD + t * 2];
    xr[t * 2 + 1] = x[(size_t)row * DD + t * 2 + 1];
    __syncthreads();

    int d0 = t, d1 = t + 256;
    double a0 = 0.0, a1 = 0.0;
    for (int k = 0; k < DD; k++) {
        double xv = (double)xr[k];
        a0 += xv * (double)W_root[(size_t)k * DD + d0];
        a1 += xv * (double)W_root[(size_t)k * DD + d1];
    }
    double h0 = fmax(a0 + (double)b_root[d0], 0.0);
    double h1 = fmax(a1 + (double)b_root[d1], 0.0);
    double so[8];
    #pragma unroll
    for (int o = 0; o < 8; o++)
        so[o] = h0 * (double)W_dec[d0 * 8 + o] + h1 * (double)W_dec[d1 * 8 + o];
    #pragma unroll
    for (int d = 1; d < 64; d <<= 1)
        #pragma unroll
        for (int o = 0; o < 8; o++) so[o] += __shfl_xor(so[o], d, 64);
    if ((t & 63) == 0) {
        #pragma unroll
        for (int o = 0; o < 8; o++) red[t >> 6][o] = so[o];
    }
    __syncthreads();
    if (t == 0) {
        double lg[8]; double mx = -1e300; int idx = 0;
        #pragma unroll
        for (int o = 0; o < 8; o++) {
            lg[o] = red[0][o] + red[1][o] + red[2][o] + red[3][o] + (double)b_dec[o];
            if (lg[o] > mx) { mx = lg[o]; idx = o; }
        }
        double ev[8], s = 0.0;
        #pragma unroll
        for (int o = 0; o < 8; o++) { ev[o] = exp(lg[o] - mx); s += ev[o]; }
        double inv = 1.0 / s;
        float4 o0, o1;
        o0.x = (float)(ev[0]*inv); o0.y = (float)(ev[1]*inv);
        o0.z = (float)(ev[2]*inv); o0.w = (float)(ev[3]*inv);
        o1.x = (float)(ev[4]*inv); o1.y = (float)(ev[5]*inv);
        o1.z = (float)(ev[6]*inv); o1.w = (float)(ev[7]*inv);
        float4* op = (float4*)(out + (size_t)row * 16);
        op[0] = o0; op[1] = o1;
        int old = route[row];
        if (idx != old) {
            atomicSub(&meta[old], 1);
            atomicAdd(&meta[idx], 1);
            route[row] = idx;
        }
    }
}

// ---------- K3: scan (256-row padding) ----------
__global__ void k_scan(int* __restrict__ meta)
{
    if (threadIdx.x == 0 && blockIdx.x == 0) {
        int run = 0, rb = 0;
        for (int e = 0; e < 8; e++) {
            int c = meta[e];
            meta[16 + e] = run;
            meta[8 + e]  = run;
            int n = (c + 255) >> 8;
            for (int j = 0; j < n; j++) meta[32 + rb + j] = e | (j << 8);
            rb += n;
            run += n << 8;
        }
        meta[24] = rb;
    }
}

// ---------- K4: scatter — ballot-ranked, 8 atomics/block ----------
__global__ __launch_bounds__(256) void k_scatter(
    const int* __restrict__ route, int* __restrict__ meta, int* __restrict__ rows_list)
{
    __shared__ int wcnt[4][8];
    __shared__ int wbase[4][8];
    int b = blockIdx.x * 256 + threadIdx.x;
    int e = route[b];
    int lane = threadIdx.x & 63, wv = threadIdx.x >> 6;
    unsigned long long mymask = 0;
    #pragma unroll
    for (int ex = 0; ex < 8; ex++) {
        unsigned long long m = __ballot(e == ex);
        if (e == ex) mymask = m;
        if (lane == 0) wcnt[wv][ex] = __popcll(m);
    }
    int myrank = __popcll(mymask & ((1ULL << lane) - 1ULL));
    __syncthreads();
    if (threadIdx.x < 8) {
        int ex = threadIdx.x;
        int c0 = wcnt[0][ex], c1 = wcnt[1][ex], c2 = wcnt[2][ex], c3 = wcnt[3][ex];
        int base = atomicAdd(&meta[8 + ex], c0 + c1 + c2 + c3);
        wbase[0][ex] = base;
        wbase[1][ex] = base + c0;
        wbase[2][ex] = base + c0 + c1;
        wbase[3][ex] = base + c0 + c1 + c2;
    }
    __syncthreads();
    rows_list[wbase[wv][e] + myrank] = b;
}

// ---------- K5: grouped leaf GEMM; BM=256, 512 threads, dbuf single-barrier K-loop ----------
__global__ __launch_bounds__(512) void k_gemm2(
    const unsigned short* __restrict__ hbuf,
    const unsigned short* __restrict__ WlT,
    const float* __restrict__ b_leaf,
    const unsigned short* __restrict__ WldT,
    const int* __restrict__ rows_list,
    const int* __restrict__ meta,
    float* __restrict__ ldec_part)           // [4][65536][8]
{
    __shared__ unsigned short smem[34816];       // 69632 B; loop: A dbuf 2x16KB + B dbuf 2x8KB; epi lh[256][136]

    int bid = blockIdx.x;                        // 1088 = 272 rb * 4 cb (swizzled)
    int rbid = (bid >> 5) * 8 + (bid & 7);
    int cb = (bid >> 3) & 3;
    if (rbid >= meta[24]) return;
    int pk = meta[32 + rbid];
    int e = pk & 255, lrb = pk >> 8;
    int poff_e = meta[16 + e], cnt_e = meta[e];
    int n0 = cb * 128;

    int t = threadIdx.x;
    int wid = t >> 6, lane = t & 63;
    int wr = wid >> 1, wc = wid & 1;
    int l15 = lane & 15, l4 = lane >> 4;

    int slot0 = poff_e + lrb * 256 + (t >> 2);
    int slot1 = slot0 + 128;
    int lastv = poff_e + cnt_e - 1;
    int grow0 = rows_list[min(slot0, lastv)];
    int grow1 = rows_list[min(slot1, lastv)];
    const unsigned short* srcA0 = hbuf + (size_t)grow0 * DD + (t & 3) * 8;
    const unsigned short* srcA1 = hbuf + (size_t)grow1 * DD + (t & 3) * 8;
    const unsigned short* srcB  = WlT + (size_t)e * DD * DD + (size_t)(n0 + (t >> 2)) * DD + (t & 3) * 8;

    f32x4 acc[4][4];
    #pragma unroll
    for (int m = 0; m < 4; m++)
        #pragma unroll
        for (int n = 0; n < 4; n++) acc[m][n] = (f32x4){0.f, 0.f, 0.f, 0.f};

    gload_lds16(srcA0, &smem[t * 8]);
    gload_lds16(srcA1, &smem[4096 + t * 8]);
    gload_lds16(srcB,  &smem[16384 + t * 8]);
    __syncthreads();

    for (int it = 0; it < 16; ++it) {
        int cur = it & 1;
        int ao = cur * 8192, bo = 16384 + cur * 4096;
        if (it < 15) {
            int k0n = (it + 1) * 32;
            int aon = (cur ^ 1) * 8192, bon = 16384 + (cur ^ 1) * 4096;
            gload_lds16(srcA0 + k0n, &smem[aon + t * 8]);
            gload_lds16(srcA1 + k0n, &smem[aon + 4096 + t * 8]);
            gload_lds16(srcB + k0n,  &smem[bon + t * 8]);
        }
        bf16x8 af[4], bfr[4];
        #pragma unroll
        for (int m = 0; m < 4; m++)
            af[m] = *(const bf16x8*)&smem[ao + (wr * 64 + m * 16 + l15) * 32 + l4 * 8];
        #pragma unroll
        for (int n = 0; n < 4; n++)
            bfr[n] = *(const bf16x8*)&smem[bo + (wc * 64 + n * 16 + l15) * 32 + l4 * 8];
        #pragma unroll
        for (int m = 0; m < 4; m++)
            #pragma unroll
            for (int n = 0; n < 4; n++)
                acc[m][n] = mfma_bf16(af[m], bfr[n], acc[m][n]);
        __syncthreads();
    }

    float bcol[4];
    #pragma unroll
    for (int n = 0; n < 4; n++) bcol[n] = b_leaf[(size_t)e * DD + n0 + wc * 64 + n * 16 + l15];
    #pragma unroll
    for (int n = 0; n < 4; n++) {
        int coll = wc * 64 + n * 16 + l15;
        #pragma unroll
        for (int m = 0; m < 4; m++) {
            int rl = wr * 64 + m * 16 + l4 * 4;
            #pragma unroll
            for (int i = 0; i < 4; i++) {
                float v = acc[m][n][i] + bcol[n];
                v = v > 0.f ? v : 0.f;
                smem[(rl + i) * 136 + coll] = f2bf(v);
            }
        }
    }
    __syncthreads();

    f32x4 acc2[2];
    acc2[0] = (f32x4){0.f, 0.f, 0.f, 0.f};
    acc2[1] = (f32x4){0.f, 0.f, 0.f, 0.f};
    #pragma unroll
    for (int kk = 0; kk < 4; kk++) {
        bf16x8 bb = *(const bf16x8*)(WldT + ((size_t)e * 16 + l15) * DD + n0 + kk * 32 + l4 * 8);
        #pragma unroll
        for (int m2 = 0; m2 < 2; m2++) {
            bf16x8 aa = *(const bf16x8*)&smem[(wid * 32 + m2 * 16 + l15) * 136 + kk * 32 + l4 * 8];
            acc2[m2] = mfma_bf16(aa, bb, acc2[m2]);
        }
    }
    if (l15 < 8) {
        #pragma unroll
        for (int m2 = 0; m2 < 2; m2++)
            #pragma unroll
            for (int i = 0; i < 4; i++) {
                int rl = wid * 32 + m2 * 16 + l4 * 4 + i;
                int s = min(poff_e + lrb * 256 + rl, lastv);
                int brow = rows_list[s];
                ldec_part[((size_t)cb * 65536 + brow) * 8 + l15] = acc2[m2][i];
            }
    }
}

// ---------- K6: sel softmax ----------
__global__ __launch_bounds__(256) void k_sel(
    const float* __restrict__ ldec_part,
    const int* __restrict__ route,
    const float* __restrict__ b_ldec,
    float* __restrict__ out)
{
    int b = blockIdx.x * 256 + threadIdx.x;
    int e = route[b];
    float lg[8];
    #pragma unroll
    for (int o = 0; o < 8; o++) lg[o] = b_ldec[e * 8 + o];
    #pragma unroll
    for (int p = 0; p < 4; p++) {
        const float4* ap = (const float4*)(ldec_part + ((size_t)p * 65536 + b) * 8);
        float4 a0 = ap[0], a1 = ap[1];
        lg[0]+=a0.x; lg[1]+=a0.y; lg[2]+=a0.z; lg[3]+=a0.w;
        lg[4]+=a1.x; lg[5]+=a1.y; lg[6]+=a1.z; lg[7]+=a1.w;
    }
    float mx = -1e30f;
    #pragma unroll
    for (int o = 0; o < 8; o++) mx = fmaxf(mx, lg[o]);
    float ev[8], s = 0.f;
    #pragma unroll
    for (int o = 0; o < 8; o++) { ev[o] = expf(lg[o] - mx); s += ev[o]; }
    float inv = 1.f / s;
    float4 o0, o1;
    o0.x = ev[0]*inv; o0.y = ev[1]*inv; o0.z = ev[2]*inv; o0.w = ev[3]*inv;
    o1.x = ev[4]*inv; o1.y = ev[5]*inv; o1.z = ev[6]*inv; o1.w = ev[7]*inv;
    float4* op = (float4*)(out + (size_t)b * 16 + 8);
    op[0] = o0; op[1] = o1;
}

extern "C" void kernel_launch(void* const* d_in, const int* in_sizes, int n_in,
                              void* d_out, int out_size, void* d_ws, size_t ws_size,
                              hipStream_t stream)
{
    const float* x      = (const float*)d_in[0];
    const float* W_root = (const float*)d_in[1];
    const float* b_root = (const float*)d_in[2];
    const float* W_dec  = (const float*)d_in[3];
    const float* b_dec  = (const float*)d_in[4];
    const float* W_leaf = (const float*)d_in[5];
    const float* b_leaf = (const float*)d_in[6];
    const float* W_ldec = (const float*)d_in[7];
    const float* b_ldec = (const float*)d_in[8];
    float* out = (float*)d_out;

    char* w = (char*)d_ws;
    unsigned short* hbuf       = (unsigned short*)(w);               // 67,108,864
    float*          logit_part = (float*)(w + 67108864);             //  8,388,608
    unsigned short* WlT        = (unsigned short*)(w + 75497472);    //  4,194,304
    unsigned short* WldT       = (unsigned short*)(w + 79691776);    //    131,072
    unsigned short* WdT        = (unsigned short*)(w + 79822848);    //     16,384
    float*          ldec_part  = (float*)(w + 79839232);             //  8,388,608
    int*            route      = (int*)(w + 88227840);               //    262,144
    int*            rows_list  = (int*)(w + 88489984);               //    273,408
    unsigned short* WrTh       = (unsigned short*)(w + 88763392);    //    524,288
    int*            rescue     = (int*)(w + 89287680);               //     32,768
    int*            meta       = (int*)(w + 89320448);               //      4,096
    const size_t WS_NEED = 89324544ULL;
    if (ws_size < WS_NEED) return;

    (void)hipMemsetAsync(meta, 0, 4096, stream);

    k_prep   <<<864,  256, 0, stream>>>(W_root, W_leaf, W_ldec, W_dec, WrTh, WlT, WldT, WdT);
    k_root   <<<1024, 512, 0, stream>>>(x, WrTh, b_root, WdT, hbuf, logit_part);
    k_dec    <<<256,  256, 0, stream>>>(logit_part, b_dec, out, route, meta, rescue);
    k_rescue <<<8192, 256, 0, stream>>>(x, W_root, b_root, W_dec, b_dec, rescue, meta, out, route);
    k_scan   <<<1,    64,  0, stream>>>(meta);
    k_scatter<<<256,  256, 0, stream>>>(route, meta, rows_list);
    k_gemm2  <<<1088, 512, 0, stream>>>(hbuf, WlT, b_leaf, WldT, rows_list, meta, ldec_part);
    k_sel    <<<256,  256, 0, stream>>>(ldec_part, route, b_ldec, out);
}

// Round 20
// 243.823 us; speedup vs baseline: 1.0170x; 1.0015x over previous
//
#include <hip/hip_runtime.h>
#include <stdint.h>

#define DD   512
#define EE   8

typedef __bf16 bf16x8 __attribute__((ext_vector_type(8)));
typedef float  f32x4  __attribute__((ext_vector_type(4)));
typedef unsigned short u16x8 __attribute__((ext_vector_type(8)));

__device__ __forceinline__ unsigned short f2bf(float f) {  // RTNE
    union { float f; unsigned int i; } v; v.f = f;
    unsigned int x = v.i;
    x += 0x7fffu + ((x >> 16) & 1u);
    return (unsigned short)(x >> 16);
}
__device__ __forceinline__ void gload_lds16(const void* g, void* l) {
    __builtin_amdgcn_global_load_lds(
        (const __attribute__((address_space(1))) unsigned int*)g,
        (__attribute__((address_space(3))) unsigned int*)l, 16, 0, 0);
}
__device__ __forceinline__ f32x4 mfma_bf16(bf16x8 a, bf16x8 b, f32x4 c) {
    return __builtin_amdgcn_mfma_f32_16x16x32_bf16(a, b, c, 0, 0, 0);
}

// ---------- K0: merged prep — W_root^T, W_leaf^T, W_ldec pad^T, W_dec pad^T ----------
__global__ __launch_bounds__(256) void k_prep(
    const float* __restrict__ W_root, const float* __restrict__ W_leaf,
    const float* __restrict__ W_ldec, const float* __restrict__ W_dec,
    unsigned short* __restrict__ WrTh, unsigned short* __restrict__ WlT,
    unsigned short* __restrict__ WldT, unsigned short* __restrict__ WdT)
{
    __shared__ unsigned short tile[64][65];
    int bid = blockIdx.x;            // 864 = 64 (wtr) + 512 (trW) + 256 (trpad) + 32 (trdec)
    int t = threadIdx.x;
    if (bid < 576) {
        const float* src;
        unsigned short* dst;
        int tl;
        if (bid < 64) {
            src = W_root; dst = WrTh; tl = bid;
        } else {
            int e = (bid - 64) >> 6;
            src = W_leaf + (size_t)e * DD * DD;
            dst = WlT + (size_t)e * DD * DD;
            tl = (bid - 64) & 63;
        }
        int tr = tl >> 3, tc = tl & 7;
        #pragma unroll
        for (int j = 0; j < 16; j++) {
            int i2 = t + j * 256; int r = i2 >> 6, c = i2 & 63;
            tile[r][c] = f2bf(src[(size_t)(tr * 64 + r) * DD + tc * 64 + c]);
        }
        __syncthreads();
        #pragma unroll
        for (int j = 0; j < 16; j++) {
            int i2 = t + j * 256; int r = i2 >> 6, c = i2 & 63;
            dst[(size_t)(tc * 64 + r) * DD + tr * 64 + c] = tile[c][r];
        }
    } else if (bid < 832) {
        int idx = (bid - 576) * 256 + t;           // 65536: WldT [e][16][512]
        int e = idx >> 13, rem = idx & 8191;
        int o = rem >> 9, k = rem & 511;
        unsigned short v = 0;
        if (o < 8) v = f2bf(W_ldec[((size_t)e * DD + k) * EE + o]);
        WldT[idx] = v;
    } else {
        int idx = (bid - 832) * 256 + t;           // 8192: WdT [16][512]
        int o = idx >> 9, k = idx & 511;
        WdT[idx] = (o < 8) ? f2bf(W_dec[(size_t)k * EE + o]) : (unsigned short)0;
    }
}

// ---------- K1: bf16 MFMA root GEMM; BM=256, 512 threads; counted-vmcnt dbuf K-loop ----------
__global__ __launch_bounds__(512) void k_root(
    const float* __restrict__ x,
    const unsigned short* __restrict__ WrTh,
    const float* __restrict__ b_root,
    const unsigned short* __restrict__ WdT,
    unsigned short* __restrict__ hbuf,
    float* __restrict__ logit_part)          // [4][65536][8], p = cb
{
    __shared__ unsigned short smem[40960];       // 81920 B; A dbuf 2x32KB + B dbuf 2x8KB; epi lh[256][136]
    float* fA = (float*)&smem[0];                // f32 buffers at idx 0 / 8192 (256x32 f32 each)
    unsigned short* bB = &smem[32768];           // u16 buffers at idx 0 / 4096 (128x32 bf16 each)

    int bid = blockIdx.x;                         // 1024 = 256 mb * 4 cb
    int mb = (bid >> 5) * 8 + (bid & 7);          // XCD-swizzled
    int cb = (bid >> 3) & 3;
    int m0 = mb * 256, n0 = cb * 128;

    int t = threadIdx.x;
    int wid = t >> 6, lane = t & 63;
    int wr = wid >> 1, wc = wid & 1;              // wr 0..3, wc 0..1
    int l15 = lane & 15, l4 = lane >> 4;

    int arow = t >> 3;                            // 0..63
    int aswz = ((t & 7) ^ (arow & 7)) * 4;
    const float* srcA = x + (size_t)(m0 + arow) * DD + aswz;
    int adst = arow * 32 + aswz;
    const unsigned short* srcB = WrTh + (size_t)(n0 + (t >> 2)) * DD + (t & 3) * 8;

    f32x4 acc[4][4];
    #pragma unroll
    for (int m = 0; m < 4; m++)
        #pragma unroll
        for (int n = 0; n < 4; n++) acc[m][n] = (f32x4){0.f, 0.f, 0.f, 0.f};

    // prologue: stage tiles 0 (buf0) and 1 (buf1); 5 loads each
    #pragma unroll
    for (int j = 0; j < 4; j++)
        gload_lds16(srcA + (size_t)j * 64 * DD, fA + adst + j * 2048);
    gload_lds16(srcB, bB + t * 8);
    #pragma unroll
    for (int j = 0; j < 4; j++)
        gload_lds16(srcA + (size_t)j * 64 * DD + 32, fA + 8192 + adst + j * 2048);
    gload_lds16(srcB + 32, bB + 4096 + t * 8);
    asm volatile("s_waitcnt vmcnt(5)" ::: "memory");   // tile0 landed (only tile1's 5 remain)
    __builtin_amdgcn_sched_barrier(0);
    __builtin_amdgcn_s_barrier();
    __builtin_amdgcn_sched_barrier(0);

    for (int it = 0; it < 16; ++it) {
        int cur = it & 1;
        int ao = cur * 8192, bo = cur * 4096;

        // compute tile it from buf[cur]
        bf16x8 fa[4], fb[4];
        #pragma unroll
        for (int m = 0; m < 4; m++) {
            int r = wr * 64 + m * 16 + l15;
            int s0 = (l4 * 2) ^ (r & 7), s1 = (l4 * 2 + 1) ^ (r & 7);
            f32x4 lo = *(const f32x4*)&fA[ao + r * 32 + s0 * 4];
            f32x4 hi = *(const f32x4*)&fA[ao + r * 32 + s1 * 4];
            #pragma unroll
            for (int j = 0; j < 4; j++) { fa[m][j] = (__bf16)lo[j]; fa[m][4 + j] = (__bf16)hi[j]; }
        }
        #pragma unroll
        for (int n = 0; n < 4; n++)
            fb[n] = *(const bf16x8*)&bB[bo + (wc * 64 + n * 16 + l15) * 32 + l4 * 8];
        #pragma unroll
        for (int m = 0; m < 4; m++)
            #pragma unroll
            for (int n = 0; n < 4; n++)
                acc[m][n] = mfma_bf16(fa[m], fb[n], acc[m][n]);

        if (it == 15) break;

        __builtin_amdgcn_s_barrier();            // all waves done reading buf[cur]
        __builtin_amdgcn_sched_barrier(0);
        if (it < 14) {                           // stage tile it+2 into buf[cur]
            int k0n = (it + 2) * 32;
            #pragma unroll
            for (int j = 0; j < 4; j++)
                gload_lds16(srcA + (size_t)j * 64 * DD + k0n, fA + ao + adst + j * 2048);
            gload_lds16(srcB + k0n, bB + bo + t * 8);
            asm volatile("s_waitcnt vmcnt(5)" ::: "memory");   // tile it+1 landed
        } else {
            asm volatile("s_waitcnt vmcnt(0)" ::: "memory");   // tile 15 landed
        }
        __builtin_amdgcn_sched_barrier(0);
        __builtin_amdgcn_s_barrier();            // all waves: next buffer ready
        __builtin_amdgcn_sched_barrier(0);
    }
    __syncthreads();                             // full drain before smem reuse

    // epilogue 1: bias + relu -> h tile (bf16) in smem as lh[256][136]
    float bcol[4];
    #pragma unroll
    for (int n = 0; n < 4; n++) bcol[n] = b_root[n0 + wc * 64 + n * 16 + l15];
    #pragma unroll
    for (int n = 0; n < 4; n++) {
        int coll = wc * 64 + n * 16 + l15;
        #pragma unroll
        for (int m = 0; m < 4; m++) {
            int rl = wr * 64 + m * 16 + l4 * 4;
            #pragma unroll
            for (int i = 0; i < 4; i++) {
                float v = acc[m][n][i] + bcol[n];
                v = v > 0.f ? v : 0.f;
                smem[(rl + i) * 136 + coll] = f2bf(v);
            }
        }
    }
    __syncthreads();

    // epilogue 2a: vectorized h store from lh (256 rows x 128 cols)
    {
        int r = t >> 1, c0s = (t & 1) * 64;
        unsigned short* dst = hbuf + (size_t)(m0 + r) * DD + n0 + c0s;
        #pragma unroll
        for (int j = 0; j < 8; j++)
            *(u16x8*)(dst + j * 8) = *(const u16x8*)&smem[r * 136 + c0s + j * 8];
    }

    // epilogue 2b: logit partial = lh_tile @ W_dec[n0:n0+128][:] via MFMA (8 waves x 32 rows)
    f32x4 acc2[2];
    acc2[0] = (f32x4){0.f, 0.f, 0.f, 0.f};
    acc2[1] = (f32x4){0.f, 0.f, 0.f, 0.f};
    #pragma unroll
    for (int kk = 0; kk < 4; kk++) {
        bf16x8 bb = *(const bf16x8*)(WdT + (size_t)l15 * DD + n0 + kk * 32 + l4 * 8);
        #pragma unroll
        for (int m2 = 0; m2 < 2; m2++) {
            bf16x8 aa = *(const bf16x8*)&smem[(wid * 32 + m2 * 16 + l15) * 136 + kk * 32 + l4 * 8];
            acc2[m2] = mfma_bf16(aa, bb, acc2[m2]);
        }
    }
    if (l15 < 8) {
        #pragma unroll
        for (int m2 = 0; m2 < 2; m2++)
            #pragma unroll
            for (int i = 0; i < 4; i++) {
                int rowg = m0 + wid * 32 + m2 * 16 + l4 * 4 + i;
                logit_part[((size_t)cb * 65536 + rowg) * 8 + l15] = acc2[m2][i];
            }
    }
}

// ---------- K2: dec softmax + route + gap-flag + fused ballot count ----------
__global__ __launch_bounds__(256) void k_dec(
    const float* __restrict__ logit_part,
    const float* __restrict__ b_dec,
    float* __restrict__ out,
    int* __restrict__ route,
    int* __restrict__ meta,
    int* __restrict__ rescue_list)
{
    __shared__ int wcnt[4][8];
    int b = blockIdx.x * 256 + threadIdx.x;
    double lg[8];
    #pragma unroll
    for (int o = 0; o < 8; o++) lg[o] = (double)b_dec[o];
    #pragma unroll
    for (int ppp = 0; ppp < 4; ppp++) {
        #pragma unroll
        for (int o = 0; o < 8; o++)
            lg[o] += (double)logit_part[((size_t)ppp * 65536 + b) * 8 + o];
    }
    double mx = -1e300, mx2 = -1e300; int idx = 0;
    #pragma unroll
    for (int o = 0; o < 8; o++) {
        if (lg[o] > mx) { mx2 = mx; mx = lg[o]; idx = o; }
        else if (lg[o] > mx2) mx2 = lg[o];
    }
    float ev[8], s = 0.f;
    #pragma unroll
    for (int o = 0; o < 8; o++) { ev[o] = expf((float)(lg[o] - mx)); s += ev[o]; }
    float inv = 1.f / s;
    float4 o0, o1;
    o0.x = ev[0]*inv; o0.y = ev[1]*inv; o0.z = ev[2]*inv; o0.w = ev[3]*inv;
    o1.x = ev[4]*inv; o1.y = ev[5]*inv; o1.z = ev[6]*inv; o1.w = ev[7]*inv;
    float4* op = (float4*)(out + (size_t)b * 16);
    op[0] = o0; op[1] = o1;
    route[b] = idx;
    if (mx - mx2 < 3e-3) {
        int pos = atomicAdd(&meta[27], 1);
        if (pos < 8192) rescue_list[pos] = b;
    }
    int lane = threadIdx.x & 63, wv = threadIdx.x >> 6;
    #pragma unroll
    for (int ex = 0; ex < 8; ex++) {
        unsigned long long m = __ballot(idx == ex);
        if (lane == 0) wcnt[wv][ex] = __popcll(m);
    }
    __syncthreads();
    if (threadIdx.x < 8) {
        int ex = threadIdx.x;
        atomicAdd(&meta[ex], wcnt[0][ex] + wcnt[1][ex] + wcnt[2][ex] + wcnt[3][ex]);
    }
}

// ---------- K2b: exact f64 rescue (dec + route + count fixup) ----------
__global__ __launch_bounds__(256) void k_rescue(
    const float* __restrict__ x,
    const float* __restrict__ W_root,
    const float* __restrict__ b_root,
    const float* __restrict__ W_dec,
    const float* __restrict__ b_dec,
    const int* __restrict__ rescue_list,
    int* __restrict__ meta,
    float* __restrict__ out,
    int* __restrict__ route)
{
    int nresc = min(meta[27], 8192);
    if ((int)blockIdx.x >= nresc) return;
    int row = rescue_list[blockIdx.x];
    int t = threadIdx.x;

    __shared__ float xr[512];
    __shared__ double red[4][8];
    xr[t * 2]     = x[(size_t)row * DD + t * 2];
    xr[t * 2 + 1] = x[(size_t)row * DD + t * 2 + 1];
    __syncthreads();

    int d0 = t, d1 = t + 256;
    double a0 = 0.0, a1 = 0.0;
    for (int k = 0; k < DD; k++) {
        double xv = (double)xr[k];
        a0 += xv * (double)W_root[(size_t)k * DD + d0];
        a1 += xv * (double)W_root[(size_t)k * DD + d1];
    }
    double h0 = fmax(a0 + (double)b_root[d0], 0.0);
    double h1 = fmax(a1 + (double)b_root[d1], 0.0);
    double so[8];
    #pragma unroll
    for (int o = 0; o < 8; o++)
        so[o] = h0 * (double)W_dec[d0 * 8 + o] + h1 * (double)W_dec[d1 * 8 + o];
    #pragma unroll
    for (int d = 1; d < 64; d <<= 1)
        #pragma unroll
        for (int o = 0; o < 8; o++) so[o] += __shfl_xor(so[o], d, 64);
    if ((t & 63) == 0) {
        #pragma unroll
        for (int o = 0; o < 8; o++) red[t >> 6][o] = so[o];
    }
    __syncthreads();
    if (t == 0) {
        double lg[8]; double mx = -1e300; int idx = 0;
        #pragma unroll
        for (int o = 0; o < 8; o++) {
            lg[o] = red[0][o] + red[1][o] + red[2][o] + red[3][o] + (double)b_dec[o];
            if (lg[o] > mx) { mx = lg[o]; idx = o; }
        }
        double ev[8], s = 0.0;
        #pragma unroll
        for (int o = 0; o < 8; o++) { ev[o] = exp(lg[o] - mx); s += ev[o]; }
        double inv = 1.0 / s;
        float4 o0, o1;
        o0.x = (float)(ev[0]*inv); o0.y = (float)(ev[1]*inv);
        o0.z = (float)(ev[2]*inv); o0.w = (float)(ev[3]*inv);
        o1.x = (float)(ev[4]*inv); o1.y = (float)(ev[5]*inv);
        o1.z = (float)(ev[6]*inv); o1.w = (float)(ev[7]*inv);
        float4* op = (float4*)(out + (size_t)row * 16);
        op[0] = o0; op[1] = o1;
        int old = route[row];
        if (idx != old) {
            atomicSub(&meta[old], 1);
            atomicAdd(&meta[idx], 1);
            route[row] = idx;
        }
    }
}

// ---------- K3: scan (256-row padding) ----------
__global__ void k_scan(int* __restrict__ meta)
{
    if (threadIdx.x == 0 && blockIdx.x == 0) {
        int run = 0, rb = 0;
        for (int e = 0; e < 8; e++) {
            int c = meta[e];
            meta[16 + e] = run;
            meta[8 + e]  = run;
            int n = (c + 255) >> 8;
            for (int j = 0; j < n; j++) meta[32 + rb + j] = e | (j << 8);
            rb += n;
            run += n << 8;
        }
        meta[24] = rb;
    }
}

// ---------- K4: scatter — ballot-ranked, 8 atomics/block ----------
__global__ __launch_bounds__(256) void k_scatter(
    const int* __restrict__ route, int* __restrict__ meta, int* __restrict__ rows_list)
{
    __shared__ int wcnt[4][8];
    __shared__ int wbase[4][8];
    int b = blockIdx.x * 256 + threadIdx.x;
    int e = route[b];
    int lane = threadIdx.x & 63, wv = threadIdx.x >> 6;
    unsigned long long mymask = 0;
    #pragma unroll
    for (int ex = 0; ex < 8; ex++) {
        unsigned long long m = __ballot(e == ex);
        if (e == ex) mymask = m;
        if (lane == 0) wcnt[wv][ex] = __popcll(m);
    }
    int myrank = __popcll(mymask & ((1ULL << lane) - 1ULL));
    __syncthreads();
    if (threadIdx.x < 8) {
        int ex = threadIdx.x;
        int c0 = wcnt[0][ex], c1 = wcnt[1][ex], c2 = wcnt[2][ex], c3 = wcnt[3][ex];
        int base = atomicAdd(&meta[8 + ex], c0 + c1 + c2 + c3);
        wbase[0][ex] = base;
        wbase[1][ex] = base + c0;
        wbase[2][ex] = base + c0 + c1;
        wbase[3][ex] = base + c0 + c1 + c2;
    }
    __syncthreads();
    rows_list[wbase[wv][e] + myrank] = b;
}

// ---------- K5: grouped leaf GEMM; BM=256, 512 threads; counted-vmcnt dbuf K-loop ----------
__global__ __launch_bounds__(512) void k_gemm2(
    const unsigned short* __restrict__ hbuf,
    const unsigned short* __restrict__ WlT,
    const float* __restrict__ b_leaf,
    const unsigned short* __restrict__ WldT,
    const int* __restrict__ rows_list,
    const int* __restrict__ meta,
    float* __restrict__ ldec_part)           // [4][65536][8]
{
    __shared__ unsigned short smem[34816];       // 69632 B; loop: A dbuf 2x16KB + B dbuf 2x8KB; epi lh[256][136]
    // A buffers: u16 idx 0 / 8192 (256x32 each); B buffers: u16 idx 16384 / 20480 (128x32 each)

    int bid = blockIdx.x;                        // 1088 = 272 rb * 4 cb (swizzled)
    int rbid = (bid >> 5) * 8 + (bid & 7);
    int cb = (bid >> 3) & 3;
    if (rbid >= meta[24]) return;
    int pk = meta[32 + rbid];
    int e = pk & 255, lrb = pk >> 8;
    int poff_e = meta[16 + e], cnt_e = meta[e];
    int n0 = cb * 128;

    int t = threadIdx.x;
    int wid = t >> 6, lane = t & 63;
    int wr = wid >> 1, wc = wid & 1;             // wr 0..3, wc 0..1
    int l15 = lane & 15, l4 = lane >> 4;

    int slot0 = poff_e + lrb * 256 + (t >> 2);
    int slot1 = slot0 + 128;
    int lastv = poff_e + cnt_e - 1;
    int grow0 = rows_list[min(slot0, lastv)];    // clamp pad slots (idempotent recompute)
    int grow1 = rows_list[min(slot1, lastv)];
    const unsigned short* srcA0 = hbuf + (size_t)grow0 * DD + (t & 3) * 8;
    const unsigned short* srcA1 = hbuf + (size_t)grow1 * DD + (t & 3) * 8;
    const unsigned short* srcB  = WlT + (size_t)e * DD * DD + (size_t)(n0 + (t >> 2)) * DD + (t & 3) * 8;

    f32x4 acc[4][4];
    #pragma unroll
    for (int m = 0; m < 4; m++)
        #pragma unroll
        for (int n = 0; n < 4; n++) acc[m][n] = (f32x4){0.f, 0.f, 0.f, 0.f};

    // prologue: stage tiles 0 (buf0) and 1 (buf1); 3 loads each
    gload_lds16(srcA0, &smem[t * 8]);
    gload_lds16(srcA1, &smem[4096 + t * 8]);
    gload_lds16(srcB,  &smem[16384 + t * 8]);
    gload_lds16(srcA0 + 32, &smem[8192 + t * 8]);
    gload_lds16(srcA1 + 32, &smem[8192 + 4096 + t * 8]);
    gload_lds16(srcB + 32,  &smem[20480 + t * 8]);
    asm volatile("s_waitcnt vmcnt(3)" ::: "memory");   // tile0 landed (only tile1's 3 remain)
    __builtin_amdgcn_sched_barrier(0);
    __builtin_amdgcn_s_barrier();
    __builtin_amdgcn_sched_barrier(0);

    for (int it = 0; it < 16; ++it) {
        int cur = it & 1;
        int ao = cur * 8192, bo = 16384 + cur * 4096;

        bf16x8 af[4], bfr[4];
        #pragma unroll
        for (int m = 0; m < 4; m++)
            af[m] = *(const bf16x8*)&smem[ao + (wr * 64 + m * 16 + l15) * 32 + l4 * 8];
        #pragma unroll
        for (int n = 0; n < 4; n++)
            bfr[n] = *(const bf16x8*)&smem[bo + (wc * 64 + n * 16 + l15) * 32 + l4 * 8];
        #pragma unroll
        for (int m = 0; m < 4; m++)
            #pragma unroll
            for (int n = 0; n < 4; n++)
                acc[m][n] = mfma_bf16(af[m], bfr[n], acc[m][n]);

        if (it == 15) break;

        __builtin_amdgcn_s_barrier();            // all waves done reading buf[cur]
        __builtin_amdgcn_sched_barrier(0);
        if (it < 14) {                           // stage tile it+2 into buf[cur]
            int k0n = (it + 2) * 32;
            gload_lds16(srcA0 + k0n, &smem[ao + t * 8]);
            gload_lds16(srcA1 + k0n, &smem[ao + 4096 + t * 8]);
            gload_lds16(srcB + k0n,  &smem[bo + t * 8]);
            asm volatile("s_waitcnt vmcnt(3)" ::: "memory");   // tile it+1 landed
        } else {
            asm volatile("s_waitcnt vmcnt(0)" ::: "memory");   // tile 15 landed
        }
        __builtin_amdgcn_sched_barrier(0);
        __builtin_amdgcn_s_barrier();            // all waves: next buffer ready
        __builtin_amdgcn_sched_barrier(0);
    }
    __syncthreads();                             // full drain before smem reuse

    // epilogue 1: bias + relu -> lh tile (bf16) in smem [256][136]
    float bcol[4];
    #pragma unroll
    for (int n = 0; n < 4; n++) bcol[n] = b_leaf[(size_t)e * DD + n0 + wc * 64 + n * 16 + l15];
    #pragma unroll
    for (int n = 0; n < 4; n++) {
        int coll = wc * 64 + n * 16 + l15;
        #pragma unroll
        for (int m = 0; m < 4; m++) {
            int rl = wr * 64 + m * 16 + l4 * 4;
            #pragma unroll
            for (int i = 0; i < 4; i++) {
                float v = acc[m][n][i] + bcol[n];
                v = v > 0.f ? v : 0.f;
                smem[(rl + i) * 136 + coll] = f2bf(v);
            }
        }
    }
    __syncthreads();

    // epilogue 2: ldec partial = lh_tile @ W_ldec[e][n0:n0+128][:] via MFMA (8 waves x 32 rows)
    f32x4 acc2[2];
    acc2[0] = (f32x4){0.f, 0.f, 0.f, 0.f};
    acc2[1] = (f32x4){0.f, 0.f, 0.f, 0.f};
    #pragma unroll
    for (int kk = 0; kk < 4; kk++) {
        bf16x8 bb = *(const bf16x8*)(WldT + ((size_t)e * 16 + l15) * DD + n0 + kk * 32 + l4 * 8);
        #pragma unroll
        for (int m2 = 0; m2 < 2; m2++) {
            bf16x8 aa = *(const bf16x8*)&smem[(wid * 32 + m2 * 16 + l15) * 136 + kk * 32 + l4 * 8];
            acc2[m2] = mfma_bf16(aa, bb, acc2[m2]);
        }
    }
    if (l15 < 8) {
        #pragma unroll
        for (int m2 = 0; m2 < 2; m2++)
            #pragma unroll
            for (int i = 0; i < 4; i++) {
                int rl = wid * 32 + m2 * 16 + l4 * 4 + i;
                int s = min(poff_e + lrb * 256 + rl, lastv);
                int brow = rows_list[s];             // pad slots: duplicate identical writes
                ldec_part[((size_t)cb * 65536 + brow) * 8 + l15] = acc2[m2][i];
            }
    }
}

// ---------- K6: sel softmax ----------
__global__ __launch_bounds__(256) void k_sel(
    const float* __restrict__ ldec_part,
    const int* __restrict__ route,
    const float* __restrict__ b_ldec,
    float* __restrict__ out)
{
    int b = blockIdx.x * 256 + threadIdx.x;
    int e = route[b];
    float lg[8];
    #pragma unroll
    for (int o = 0; o < 8; o++) lg[o] = b_ldec[e * 8 + o];
    #pragma unroll
    for (int p = 0; p < 4; p++) {
        const float4* ap = (const float4*)(ldec_part + ((size_t)p * 65536 + b) * 8);
        float4 a0 = ap[0], a1 = ap[1];
        lg[0]+=a0.x; lg[1]+=a0.y; lg[2]+=a0.z; lg[3]+=a0.w;
        lg[4]+=a1.x; lg[5]+=a1.y; lg[6]+=a1.z; lg[7]+=a1.w;
    }
    float mx = -1e30f;
    #pragma unroll
    for (int o = 0; o < 8; o++) mx = fmaxf(mx, lg[o]);
    float ev[8], s = 0.f;
    #pragma unroll
    for (int o = 0; o < 8; o++) { ev[o] = expf(lg[o] - mx); s += ev[o]; }
    float inv = 1.f / s;
    float4 o0, o1;
    o0.x = ev[0]*inv; o0.y = ev[1]*inv; o0.z = ev[2]*inv; o0.w = ev[3]*inv;
    o1.x = ev[4]*inv; o1.y = ev[5]*inv; o1.z = ev[6]*inv; o1.w = ev[7]*inv;
    float4* op = (float4*)(out + (size_t)b * 16 + 8);
    op[0] = o0; op[1] = o1;
}

extern "C" void kernel_launch(void* const* d_in, const int* in_sizes, int n_in,
                              void* d_out, int out_size, void* d_ws, size_t ws_size,
                              hipStream_t stream)
{
    const float* x      = (const float*)d_in[0];
    const float* W_root = (const float*)d_in[1];
    const float* b_root = (const float*)d_in[2];
    const float* W_dec  = (const float*)d_in[3];
    const float* b_dec  = (const float*)d_in[4];
    const float* W_leaf = (const float*)d_in[5];
    const float* b_leaf = (const float*)d_in[6];
    const float* W_ldec = (const float*)d_in[7];
    const float* b_ldec = (const float*)d_in[8];
    float* out = (float*)d_out;

    char* w = (char*)d_ws;
    unsigned short* hbuf       = (unsigned short*)(w);               // 67,108,864
    float*          logit_part = (float*)(w + 67108864);             //  8,388,608
    unsigned short* WlT        = (unsigned short*)(w + 75497472);    //  4,194,304
    unsigned short* WldT       = (unsigned short*)(w + 79691776);    //    131,072
    unsigned short* WdT        = (unsigned short*)(w + 79822848);    //     16,384
    float*          ldec_part  = (float*)(w + 79839232);             //  8,388,608
    int*            route      = (int*)(w + 88227840);               //    262,144
    int*            rows_list  = (int*)(w + 88489984);               //    273,408
    unsigned short* WrTh       = (unsigned short*)(w + 88763392);    //    524,288
    int*            rescue     = (int*)(w + 89287680);               //     32,768
    int*            meta       = (int*)(w + 89320448);               //      4,096
    const size_t WS_NEED = 89324544ULL;
    if (ws_size < WS_NEED) return;

    (void)hipMemsetAsync(meta, 0, 4096, stream);

    k_prep   <<<864,  256, 0, stream>>>(W_root, W_leaf, W_ldec, W_dec, WrTh, WlT, WldT, WdT);
    k_root   <<<1024, 512, 0, stream>>>(x, WrTh, b_root, WdT, hbuf, logit_part);
    k_dec    <<<256,  256, 0, stream>>>(logit_part, b_dec, out, route, meta, rescue);
    k_rescue <<<8192, 256, 0, stream>>>(x, W_root, b_root, W_dec, b_dec, rescue, meta, out, route);
    k_scan   <<<1,    64,  0, stream>>>(meta);
    k_scatter<<<256,  256, 0, stream>>>(route, meta, rows_list);
    k_gemm2  <<<1088, 512, 0, stream>>>(hbuf, WlT, b_leaf, WldT, rows_list, meta, ldec_part);
    k_sel    <<<256,  256, 0, stream>>>(ldec_part, route, b_ldec, out);
}

// Round 21
// 240.444 us; speedup vs baseline: 1.0313x; 1.0141x over previous
//
#include <hip/hip_runtime.h>
#include <stdint.h>

#define DD   512
#define EE   8

typedef __bf16 bf16x8 __attribute__((ext_vector_type(8)));
typedef float  f32x4  __attribute__((ext_vector_type(4)));
typedef unsigned short u16x8 __attribute__((ext_vector_type(8)));

__device__ __forceinline__ unsigned short f2bf(float f) {  // RTNE
    union { float f; unsigned int i; } v; v.f = f;
    unsigned int x = v.i;
    x += 0x7fffu + ((x >> 16) & 1u);
    return (unsigned short)(x >> 16);
}
__device__ __forceinline__ void gload_lds16(const void* g, void* l) {
    __builtin_amdgcn_global_load_lds(
        (const __attribute__((address_space(1))) unsigned int*)g,
        (__attribute__((address_space(3))) unsigned int*)l, 16, 0, 0);
}
__device__ __forceinline__ f32x4 mfma_bf16(bf16x8 a, bf16x8 b, f32x4 c) {
    return __builtin_amdgcn_mfma_f32_16x16x32_bf16(a, b, c, 0, 0, 0);
}

// ---------- K0: merged prep — W_root^T, W_leaf^T, W_ldec pad^T, W_dec pad^T ----------
__global__ __launch_bounds__(256) void k_prep(
    const float* __restrict__ W_root, const float* __restrict__ W_leaf,
    const float* __restrict__ W_ldec, const float* __restrict__ W_dec,
    unsigned short* __restrict__ WrTh, unsigned short* __restrict__ WlT,
    unsigned short* __restrict__ WldT, unsigned short* __restrict__ WdT)
{
    __shared__ unsigned short tile[64][65];
    int bid = blockIdx.x;            // 864 = 64 (wtr) + 512 (trW) + 256 (trpad) + 32 (trdec)
    int t = threadIdx.x;
    if (bid < 576) {
        const float* src;
        unsigned short* dst;
        int tl;
        if (bid < 64) {
            src = W_root; dst = WrTh; tl = bid;
        } else {
            int e = (bid - 64) >> 6;
            src = W_leaf + (size_t)e * DD * DD;
            dst = WlT + (size_t)e * DD * DD;
            tl = (bid - 64) & 63;
        }
        int tr = tl >> 3, tc = tl & 7;
        #pragma unroll
        for (int j = 0; j < 16; j++) {
            int i2 = t + j * 256; int r = i2 >> 6, c = i2 & 63;
            tile[r][c] = f2bf(src[(size_t)(tr * 64 + r) * DD + tc * 64 + c]);
        }
        __syncthreads();
        #pragma unroll
        for (int j = 0; j < 16; j++) {
            int i2 = t + j * 256; int r = i2 >> 6, c = i2 & 63;
            dst[(size_t)(tc * 64 + r) * DD + tr * 64 + c] = tile[c][r];
        }
    } else if (bid < 832) {
        int idx = (bid - 576) * 256 + t;           // 65536: WldT [e][16][512]
        int e = idx >> 13, rem = idx & 8191;
        int o = rem >> 9, k = rem & 511;
        unsigned short v = 0;
        if (o < 8) v = f2bf(W_ldec[((size_t)e * DD + k) * EE + o]);
        WldT[idx] = v;
    } else {
        int idx = (bid - 832) * 256 + t;           // 8192: WdT [16][512]
        int o = idx >> 9, k = idx & 511;
        WdT[idx] = (o < 8) ? f2bf(W_dec[(size_t)k * EE + o]) : (unsigned short)0;
    }
}

// ---------- K1: bf16 MFMA root GEMM; BM=256, 512 threads; counted-vmcnt dbuf K-loop ----------
// A staged f32 (pre-swizzled source); B bf16 with chunk-XOR source/read swizzle (2-way banks).
__global__ __launch_bounds__(512) void k_root(
    const float* __restrict__ x,
    const unsigned short* __restrict__ WrTh,
    const float* __restrict__ b_root,
    const unsigned short* __restrict__ WdT,
    unsigned short* __restrict__ hbuf,
    float* __restrict__ logit_part)          // [4][65536][8], p = cb
{
    __shared__ unsigned short smem[40960];       // 81920 B; A dbuf 2x32KB + B dbuf 2x8KB; epi lh[256][136]
    float* fA = (float*)&smem[0];                // f32 buffers at idx 0 / 8192 (256x32 f32 each)
    unsigned short* bB = &smem[32768];           // u16 buffers at idx 0 / 4096 (128x32 bf16 each)

    int bid = blockIdx.x;                         // 1024 = 256 mb * 4 cb
    int mb = (bid >> 5) * 8 + (bid & 7);          // XCD-swizzled
    int cb = (bid >> 3) & 3;
    int m0 = mb * 256, n0 = cb * 128;

    int t = threadIdx.x;
    int wid = t >> 6, lane = t & 63;
    int wr = wid >> 1, wc = wid & 1;              // wr 0..3, wc 0..1
    int l15 = lane & 15, l4 = lane >> 4;

    int arow = t >> 3;                            // 0..63
    int aswz = ((t & 7) ^ (arow & 7)) * 4;
    const float* srcA = x + (size_t)(m0 + arow) * DD + aswz;
    int adst = arow * 32 + aswz;
    // B: pre-swizzled source slot (chunk ^= (row>>1)&3), row = t>>2
    int bslot = ((t & 3) ^ ((t >> 3) & 3)) * 8;
    const unsigned short* srcB = WrTh + (size_t)(n0 + (t >> 2)) * DD + bslot;

    f32x4 acc[4][4];
    #pragma unroll
    for (int m = 0; m < 4; m++)
        #pragma unroll
        for (int n = 0; n < 4; n++) acc[m][n] = (f32x4){0.f, 0.f, 0.f, 0.f};

    // prologue: stage tiles 0 (buf0) and 1 (buf1); 5 loads each
    #pragma unroll
    for (int j = 0; j < 4; j++)
        gload_lds16(srcA + (size_t)j * 64 * DD, fA + adst + j * 2048);
    gload_lds16(srcB, bB + t * 8);
    #pragma unroll
    for (int j = 0; j < 4; j++)
        gload_lds16(srcA + (size_t)j * 64 * DD + 32, fA + 8192 + adst + j * 2048);
    gload_lds16(srcB + 32, bB + 4096 + t * 8);
    asm volatile("s_waitcnt vmcnt(5)" ::: "memory");   // tile0 landed (only tile1's 5 remain)
    __builtin_amdgcn_sched_barrier(0);
    __builtin_amdgcn_s_barrier();
    __builtin_amdgcn_sched_barrier(0);

    for (int it = 0; it < 16; ++it) {
        int cur = it & 1;
        int ao = cur * 8192, bo = cur * 4096;

        // compute tile it from buf[cur]
        bf16x8 fa[4], fb[4];
        #pragma unroll
        for (int m = 0; m < 4; m++) {
            int r = wr * 64 + m * 16 + l15;
            int s0 = (l4 * 2) ^ (r & 7), s1 = (l4 * 2 + 1) ^ (r & 7);
            f32x4 lo = *(const f32x4*)&fA[ao + r * 32 + s0 * 4];
            f32x4 hi = *(const f32x4*)&fA[ao + r * 32 + s1 * 4];
            #pragma unroll
            for (int j = 0; j < 4; j++) { fa[m][j] = (__bf16)lo[j]; fa[m][4 + j] = (__bf16)hi[j]; }
        }
        #pragma unroll
        for (int n = 0; n < 4; n++) {
            int rb = wc * 64 + n * 16 + l15;
            fb[n] = *(const bf16x8*)&bB[bo + rb * 32 + (l4 ^ ((rb >> 1) & 3)) * 8];
        }
        #pragma unroll
        for (int m = 0; m < 4; m++)
            #pragma unroll
            for (int n = 0; n < 4; n++)
                acc[m][n] = mfma_bf16(fa[m], fb[n], acc[m][n]);

        if (it == 15) break;

        __builtin_amdgcn_s_barrier();            // all waves done reading buf[cur]
        __builtin_amdgcn_sched_barrier(0);
        if (it < 14) {                           // stage tile it+2 into buf[cur]
            int k0n = (it + 2) * 32;
            #pragma unroll
            for (int j = 0; j < 4; j++)
                gload_lds16(srcA + (size_t)j * 64 * DD + k0n, fA + ao + adst + j * 2048);
            gload_lds16(srcB + k0n, bB + bo + t * 8);
            asm volatile("s_waitcnt vmcnt(5)" ::: "memory");   // tile it+1 landed
        } else {
            asm volatile("s_waitcnt vmcnt(0)" ::: "memory");   // tile 15 landed
        }
        __builtin_amdgcn_sched_barrier(0);
        __builtin_amdgcn_s_barrier();            // all waves: next buffer ready
        __builtin_amdgcn_sched_barrier(0);
    }
    __syncthreads();                             // full drain before smem reuse

    // epilogue 1: bias + relu -> h tile (bf16) in smem as lh[256][136]
    float bcol[4];
    #pragma unroll
    for (int n = 0; n < 4; n++) bcol[n] = b_root[n0 + wc * 64 + n * 16 + l15];
    #pragma unroll
    for (int n = 0; n < 4; n++) {
        int coll = wc * 64 + n * 16 + l15;
        #pragma unroll
        for (int m = 0; m < 4; m++) {
            int rl = wr * 64 + m * 16 + l4 * 4;
            #pragma unroll
            for (int i = 0; i < 4; i++) {
                float v = acc[m][n][i] + bcol[n];
                v = v > 0.f ? v : 0.f;
                smem[(rl + i) * 136 + coll] = f2bf(v);
            }
        }
    }
    __syncthreads();

    // epilogue 2a: vectorized h store from lh (256 rows x 128 cols)
    {
        int r = t >> 1, c0s = (t & 1) * 64;
        unsigned short* dst = hbuf + (size_t)(m0 + r) * DD + n0 + c0s;
        #pragma unroll
        for (int j = 0; j < 8; j++)
            *(u16x8*)(dst + j * 8) = *(const u16x8*)&smem[r * 136 + c0s + j * 8];
    }

    // epilogue 2b: logit partial = lh_tile @ W_dec[n0:n0+128][:] via MFMA (8 waves x 32 rows)
    f32x4 acc2[2];
    acc2[0] = (f32x4){0.f, 0.f, 0.f, 0.f};
    acc2[1] = (f32x4){0.f, 0.f, 0.f, 0.f};
    #pragma unroll
    for (int kk = 0; kk < 4; kk++) {
        bf16x8 bb = *(const bf16x8*)(WdT + (size_t)l15 * DD + n0 + kk * 32 + l4 * 8);
        #pragma unroll
        for (int m2 = 0; m2 < 2; m2++) {
            bf16x8 aa = *(const bf16x8*)&smem[(wid * 32 + m2 * 16 + l15) * 136 + kk * 32 + l4 * 8];
            acc2[m2] = mfma_bf16(aa, bb, acc2[m2]);
        }
    }
    if (l15 < 8) {
        #pragma unroll
        for (int m2 = 0; m2 < 2; m2++)
            #pragma unroll
            for (int i = 0; i < 4; i++) {
                int rowg = m0 + wid * 32 + m2 * 16 + l4 * 4 + i;
                logit_part[((size_t)cb * 65536 + rowg) * 8 + l15] = acc2[m2][i];
            }
    }
}

// ---------- K2: dec softmax + route + gap-flag + fused ballot count ----------
__global__ __launch_bounds__(256) void k_dec(
    const float* __restrict__ logit_part,
    const float* __restrict__ b_dec,
    float* __restrict__ out,
    int* __restrict__ route,
    int* __restrict__ meta,
    int* __restrict__ rescue_list)
{
    __shared__ int wcnt[4][8];
    int b = blockIdx.x * 256 + threadIdx.x;
    double lg[8];
    #pragma unroll
    for (int o = 0; o < 8; o++) lg[o] = (double)b_dec[o];
    #pragma unroll
    for (int ppp = 0; ppp < 4; ppp++) {
        #pragma unroll
        for (int o = 0; o < 8; o++)
            lg[o] += (double)logit_part[((size_t)ppp * 65536 + b) * 8 + o];
    }
    double mx = -1e300, mx2 = -1e300; int idx = 0;
    #pragma unroll
    for (int o = 0; o < 8; o++) {
        if (lg[o] > mx) { mx2 = mx; mx = lg[o]; idx = o; }
        else if (lg[o] > mx2) mx2 = lg[o];
    }
    float ev[8], s = 0.f;
    #pragma unroll
    for (int o = 0; o < 8; o++) { ev[o] = expf((float)(lg[o] - mx)); s += ev[o]; }
    float inv = 1.f / s;
    float4 o0, o1;
    o0.x = ev[0]*inv; o0.y = ev[1]*inv; o0.z = ev[2]*inv; o0.w = ev[3]*inv;
    o1.x = ev[4]*inv; o1.y = ev[5]*inv; o1.z = ev[6]*inv; o1.w = ev[7]*inv;
    float4* op = (float4*)(out + (size_t)b * 16);
    op[0] = o0; op[1] = o1;
    route[b] = idx;
    if (mx - mx2 < 3e-3) {
        int pos = atomicAdd(&meta[27], 1);
        if (pos < 8192) rescue_list[pos] = b;
    }
    int lane = threadIdx.x & 63, wv = threadIdx.x >> 6;
    #pragma unroll
    for (int ex = 0; ex < 8; ex++) {
        unsigned long long m = __ballot(idx == ex);
        if (lane == 0) wcnt[wv][ex] = __popcll(m);
    }
    __syncthreads();
    if (threadIdx.x < 8) {
        int ex = threadIdx.x;
        atomicAdd(&meta[ex], wcnt[0][ex] + wcnt[1][ex] + wcnt[2][ex] + wcnt[3][ex]);
    }
}

// ---------- K2b: exact f64 rescue (dec + route + count fixup) ----------
__global__ __launch_bounds__(256) void k_rescue(
    const float* __restrict__ x,
    const float* __restrict__ W_root,
    const float* __restrict__ b_root,
    const float* __restrict__ W_dec,
    const float* __restrict__ b_dec,
    const int* __restrict__ rescue_list,
    int* __restrict__ meta,
    float* __restrict__ out,
    int* __restrict__ route)
{
    int nresc = min(meta[27], 8192);
    if ((int)blockIdx.x >= nresc) return;
    int row = rescue_list[blockIdx.x];
    int t = threadIdx.x;

    __shared__ float xr[512];
    __shared__ double red[4][8];
    xr[t * 2]     = x[(size_t)row * DD + t * 2];
    xr[t * 2 + 1] = x[(size_t)row * DD + t * 2 + 1];
    __syncthreads();

    int d0 = t, d1 = t + 256;
    double a0 = 0.0, a1 = 0.0;
    for (int k = 0; k < DD; k++) {
        double xv = (double)xr[k];
        a0 += xv * (double)W_root[(size_t)k * DD + d0];
        a1 += xv * (double)W_root[(size_t)k * DD + d1];
    }
    double h0 = fmax(a0 + (double)b_root[d0], 0.0);
    double h1 = fmax(a1 + (double)b_root[d1], 0.0);
    double so[8];
    #pragma unroll
    for (int o = 0; o < 8; o++)
        so[o] = h0 * (double)W_dec[d0 * 8 + o] + h1 * (double)W_dec[d1 * 8 + o];
    #pragma unroll
    for (int d = 1; d < 64; d <<= 1)
        #pragma unroll
        for (int o = 0; o < 8; o++) so[o] += __shfl_xor(so[o], d, 64);
    if ((t & 63) == 0) {
        #pragma unroll
        for (int o = 0; o < 8; o++) red[t >> 6][o] = so[o];
    }
    __syncthreads();
    if (t == 0) {
        double lg[8]; double mx = -1e300; int idx = 0;
        #pragma unroll
        for (int o = 0; o < 8; o++) {
            lg[o] = red[0][o] + red[1][o] + red[2][o] + red[3][o] + (double)b_dec[o];
            if (lg[o] > mx) { mx = lg[o]; idx = o; }
        }
        double ev[8], s = 0.0;
        #pragma unroll
        for (int o = 0; o < 8; o++) { ev[o] = exp(lg[o] - mx); s += ev[o]; }
        double inv = 1.0 / s;
        float4 o0, o1;
        o0.x = (float)(ev[0]*inv); o0.y = (float)(ev[1]*inv);
        o0.z = (float)(ev[2]*inv); o0.w = (float)(ev[3]*inv);
        o1.x = (float)(ev[4]*inv); o1.y = (float)(ev[5]*inv);
        o1.z = (float)(ev[6]*inv); o1.w = (float)(ev[7]*inv);
        float4* op = (float4*)(out + (size_t)row * 16);
        op[0] = o0; op[1] = o1;
        int old = route[row];
        if (idx != old) {
            atomicSub(&meta[old], 1);
            atomicAdd(&meta[idx], 1);
            route[row] = idx;
        }
    }
}

// ---------- K3: scan (256-row padding) ----------
__global__ void k_scan(int* __restrict__ meta)
{
    if (threadIdx.x == 0 && blockIdx.x == 0) {
        int run = 0, rb = 0;
        for (int e = 0; e < 8; e++) {
            int c = meta[e];
            meta[16 + e] = run;
            meta[8 + e]  = run;
            int n = (c + 255) >> 8;
            for (int j = 0; j < n; j++) meta[32 + rb + j] = e | (j << 8);
            rb += n;
            run += n << 8;
        }
        meta[24] = rb;
    }
}

// ---------- K4: scatter — ballot-ranked, 8 atomics/block ----------
__global__ __launch_bounds__(256) void k_scatter(
    const int* __restrict__ route, int* __restrict__ meta, int* __restrict__ rows_list)
{
    __shared__ int wcnt[4][8];
    __shared__ int wbase[4][8];
    int b = blockIdx.x * 256 + threadIdx.x;
    int e = route[b];
    int lane = threadIdx.x & 63, wv = threadIdx.x >> 6;
    unsigned long long mymask = 0;
    #pragma unroll
    for (int ex = 0; ex < 8; ex++) {
        unsigned long long m = __ballot(e == ex);
        if (e == ex) mymask = m;
        if (lane == 0) wcnt[wv][ex] = __popcll(m);
    }
    int myrank = __popcll(mymask & ((1ULL << lane) - 1ULL));
    __syncthreads();
    if (threadIdx.x < 8) {
        int ex = threadIdx.x;
        int c0 = wcnt[0][ex], c1 = wcnt[1][ex], c2 = wcnt[2][ex], c3 = wcnt[3][ex];
        int base = atomicAdd(&meta[8 + ex], c0 + c1 + c2 + c3);
        wbase[0][ex] = base;
        wbase[1][ex] = base + c0;
        wbase[2][ex] = base + c0 + c1;
        wbase[3][ex] = base + c0 + c1 + c2;
    }
    __syncthreads();
    rows_list[wbase[wv][e] + myrank] = b;
}

// ---------- K5: grouped leaf GEMM; BM=256, 512 threads; counted-vmcnt dbuf K-loop ----------
// A and B staged with chunk-XOR source swizzle; reads apply matching XOR (2-way banks).
__global__ __launch_bounds__(512) void k_gemm2(
    const unsigned short* __restrict__ hbuf,
    const unsigned short* __restrict__ WlT,
    const float* __restrict__ b_leaf,
    const unsigned short* __restrict__ WldT,
    const int* __restrict__ rows_list,
    const int* __restrict__ meta,
    float* __restrict__ ldec_part)           // [4][65536][8]
{
    __shared__ unsigned short smem[34816];       // 69632 B; loop: A dbuf 2x16KB + B dbuf 2x8KB; epi lh[256][136]
    // A buffers: u16 idx 0 / 8192 (256x32 each); B buffers: u16 idx 16384 / 20480 (128x32 each)

    int bid = blockIdx.x;                        // 1088 = 272 rb * 4 cb (swizzled)
    int rbid = (bid >> 5) * 8 + (bid & 7);
    int cb = (bid >> 3) & 3;
    if (rbid >= meta[24]) return;
    int pk = meta[32 + rbid];
    int e = pk & 255, lrb = pk >> 8;
    int poff_e = meta[16 + e], cnt_e = meta[e];
    int n0 = cb * 128;

    int t = threadIdx.x;
    int wid = t >> 6, lane = t & 63;
    int wr = wid >> 1, wc = wid & 1;             // wr 0..3, wc 0..1
    int l15 = lane & 15, l4 = lane >> 4;

    int slot0 = poff_e + lrb * 256 + (t >> 2);
    int slot1 = slot0 + 128;
    int lastv = poff_e + cnt_e - 1;
    int grow0 = rows_list[min(slot0, lastv)];    // clamp pad slots (idempotent recompute)
    int grow1 = rows_list[min(slot1, lastv)];
    int kslot = ((t & 3) ^ ((t >> 3) & 3)) * 8;  // chunk-XOR source swizzle (row = t>>2; +128 preserves (row>>1)&3)
    const unsigned short* srcA0 = hbuf + (size_t)grow0 * DD + kslot;
    const unsigned short* srcA1 = hbuf + (size_t)grow1 * DD + kslot;
    const unsigned short* srcB  = WlT + (size_t)e * DD * DD + (size_t)(n0 + (t >> 2)) * DD + kslot;

    f32x4 acc[4][4];
    #pragma unroll
    for (int m = 0; m < 4; m++)
        #pragma unroll
        for (int n = 0; n < 4; n++) acc[m][n] = (f32x4){0.f, 0.f, 0.f, 0.f};

    // prologue: stage tiles 0 (buf0) and 1 (buf1); 3 loads each
    gload_lds16(srcA0, &smem[t * 8]);
    gload_lds16(srcA1, &smem[4096 + t * 8]);
    gload_lds16(srcB,  &smem[16384 + t * 8]);
    gload_lds16(srcA0 + 32, &smem[8192 + t * 8]);
    gload_lds16(srcA1 + 32, &smem[8192 + 4096 + t * 8]);
    gload_lds16(srcB + 32,  &smem[20480 + t * 8]);
    asm volatile("s_waitcnt vmcnt(3)" ::: "memory");   // tile0 landed (only tile1's 3 remain)
    __builtin_amdgcn_sched_barrier(0);
    __builtin_amdgcn_s_barrier();
    __builtin_amdgcn_sched_barrier(0);

    for (int it = 0; it < 16; ++it) {
        int cur = it & 1;
        int ao = cur * 8192, bo = 16384 + cur * 4096;

        bf16x8 af[4], bfr[4];
        #pragma unroll
        for (int m = 0; m < 4; m++) {
            int ra = wr * 64 + m * 16 + l15;
            af[m] = *(const bf16x8*)&smem[ao + ra * 32 + (l4 ^ ((ra >> 1) & 3)) * 8];
        }
        #pragma unroll
        for (int n = 0; n < 4; n++) {
            int rb = wc * 64 + n * 16 + l15;
            bfr[n] = *(const bf16x8*)&smem[bo + rb * 32 + (l4 ^ ((rb >> 1) & 3)) * 8];
        }
        #pragma unroll
        for (int m = 0; m < 4; m++)
            #pragma unroll
            for (int n = 0; n < 4; n++)
                acc[m][n] = mfma_bf16(af[m], bfr[n], acc[m][n]);

        if (it == 15) break;

        __builtin_amdgcn_s_barrier();            // all waves done reading buf[cur]
        __builtin_amdgcn_sched_barrier(0);
        if (it < 14) {                           // stage tile it+2 into buf[cur]
            int k0n = (it + 2) * 32;
            gload_lds16(srcA0 + k0n, &smem[ao + t * 8]);
            gload_lds16(srcA1 + k0n, &smem[ao + 4096 + t * 8]);
            gload_lds16(srcB + k0n,  &smem[bo + t * 8]);
            asm volatile("s_waitcnt vmcnt(3)" ::: "memory");   // tile it+1 landed
        } else {
            asm volatile("s_waitcnt vmcnt(0)" ::: "memory");   // tile 15 landed
        }
        __builtin_amdgcn_sched_barrier(0);
        __builtin_amdgcn_s_barrier();            // all waves: next buffer ready
        __builtin_amdgcn_sched_barrier(0);
    }
    __syncthreads();                             // full drain before smem reuse

    // epilogue 1: bias + relu -> lh tile (bf16) in smem [256][136]
    float bcol[4];
    #pragma unroll
    for (int n = 0; n < 4; n++) bcol[n] = b_leaf[(size_t)e * DD + n0 + wc * 64 + n * 16 + l15];
    #pragma unroll
    for (int n = 0; n < 4; n++) {
        int coll = wc * 64 + n * 16 + l15;
        #pragma unroll
        for (int m = 0; m < 4; m++) {
            int rl = wr * 64 + m * 16 + l4 * 4;
            #pragma unroll
            for (int i = 0; i < 4; i++) {
                float v = acc[m][n][i] + bcol[n];
                v = v > 0.f ? v : 0.f;
                smem[(rl + i) * 136 + coll] = f2bf(v);
            }
        }
    }
    __syncthreads();

    // epilogue 2: ldec partial = lh_tile @ W_ldec[e][n0:n0+128][:] via MFMA (8 waves x 32 rows)
    f32x4 acc2[2];
    acc2[0] = (f32x4){0.f, 0.f, 0.f, 0.f};
    acc2[1] = (f32x4){0.f, 0.f, 0.f, 0.f};
    #pragma unroll
    for (int kk = 0; kk < 4; kk++) {
        bf16x8 bb = *(const bf16x8*)(WldT + ((size_t)e * 16 + l15) * DD + n0 + kk * 32 + l4 * 8);
        #pragma unroll
        for (int m2 = 0; m2 < 2; m2++) {
            bf16x8 aa = *(const bf16x8*)&smem[(wid * 32 + m2 * 16 + l15) * 136 + kk * 32 + l4 * 8];
            acc2[m2] = mfma_bf16(aa, bb, acc2[m2]);
        }
    }
    if (l15 < 8) {
        #pragma unroll
        for (int m2 = 0; m2 < 2; m2++)
            #pragma unroll
            for (int i = 0; i < 4; i++) {
                int rl = wid * 32 + m2 * 16 + l4 * 4 + i;
                int s = min(poff_e + lrb * 256 + rl, lastv);
                int brow = rows_list[s];             // pad slots: duplicate identical writes
                ldec_part[((size_t)cb * 65536 + brow) * 8 + l15] = acc2[m2][i];
            }
    }
}

// ---------- K6: sel softmax ----------
__global__ __launch_bounds__(256) void k_sel(
    const float* __restrict__ ldec_part,
    const int* __restrict__ route,
    const float* __restrict__ b_ldec,
    float* __restrict__ out)
{
    int b = blockIdx.x * 256 + threadIdx.x;
    int e = route[b];
    float lg[8];
    #pragma unroll
    for (int o = 0; o < 8; o++) lg[o] = b_ldec[e * 8 + o];
    #pragma unroll
    for (int p = 0; p < 4; p++) {
        const float4* ap = (const float4*)(ldec_part + ((size_t)p * 65536 + b) * 8);
        float4 a0 = ap[0], a1 = ap[1];
        lg[0]+=a0.x; lg[1]+=a0.y; lg[2]+=a0.z; lg[3]+=a0.w;
        lg[4]+=a1.x; lg[5]+=a1.y; lg[6]+=a1.z; lg[7]+=a1.w;
    }
    float mx = -1e30f;
    #pragma unroll
    for (int o = 0; o < 8; o++) mx = fmaxf(mx, lg[o]);
    float ev[8], s = 0.f;
    #pragma unroll
    for (int o = 0; o < 8; o++) { ev[o] = expf(lg[o] - mx); s += ev[o]; }
    float inv = 1.f / s;
    float4 o0, o1;
    o0.x = ev[0]*inv; o0.y = ev[1]*inv; o0.z = ev[2]*inv; o0.w = ev[3]*inv;
    o1.x = ev[4]*inv; o1.y = ev[5]*inv; o1.z = ev[6]*inv; o1.w = ev[7]*inv;
    float4* op = (float4*)(out + (size_t)b * 16 + 8);
    op[0] = o0; op[1] = o1;
}

extern "C" void kernel_launch(void* const* d_in, const int* in_sizes, int n_in,
                              void* d_out, int out_size, void* d_ws, size_t ws_size,
                              hipStream_t stream)
{
    const float* x      = (const float*)d_in[0];
    const float* W_root = (const float*)d_in[1];
    const float* b_root = (const float*)d_in[2];
    const float* W_dec  = (const float*)d_in[3];
    const float* b_dec  = (const float*)d_in[4];
    const float* W_leaf = (const float*)d_in[5];
    const float* b_leaf = (const float*)d_in[6];
    const float* W_ldec = (const float*)d_in[7];
    const float* b_ldec = (const float*)d_in[8];
    float* out = (float*)d_out;

    char* w = (char*)d_ws;
    unsigned short* hbuf       = (unsigned short*)(w);               // 67,108,864
    float*          logit_part = (float*)(w + 67108864);             //  8,388,608
    unsigned short* WlT        = (unsigned short*)(w + 75497472);    //  4,194,304
    unsigned short* WldT       = (unsigned short*)(w + 79691776);    //    131,072
    unsigned short* WdT        = (unsigned short*)(w + 79822848);    //     16,384
    float*          ldec_part  = (float*)(w + 79839232);             //  8,388,608
    int*            route      = (int*)(w + 88227840);               //    262,144
    int*            rows_list  = (int*)(w + 88489984);               //    273,408
    unsigned short* WrTh       = (unsigned short*)(w + 88763392);    //    524,288
    int*            rescue     = (int*)(w + 89287680);               //     32,768
    int*            meta       = (int*)(w + 89320448);               //      4,096
    const size_t WS_NEED = 89324544ULL;
    if (ws_size < WS_NEED) return;

    (void)hipMemsetAsync(meta, 0, 4096, stream);

    k_prep   <<<864,  256, 0, stream>>>(W_root, W_leaf, W_ldec, W_dec, WrTh, WlT, WldT, WdT);
    k_root   <<<1024, 512, 0, stream>>>(x, WrTh, b_root, WdT, hbuf, logit_part);
    k_dec    <<<256,  256, 0, stream>>>(logit_part, b_dec, out, route, meta, rescue);
    k_rescue <<<8192, 256, 0, stream>>>(x, W_root, b_root, W_dec, b_dec, rescue, meta, out, route);
    k_scan   <<<1,    64,  0, stream>>>(meta);
    k_scatter<<<256,  256, 0, stream>>>(route, meta, rows_list);
    k_gemm2  <<<1088, 512, 0, stream>>>(hbuf, WlT, b_leaf, WldT, rows_list, meta, ldec_part);
    k_sel    <<<256,  256, 0, stream>>>(ldec_part, route, b_ldec, out);
}